// Round 7
// baseline (959.974 us; speedup 1.0000x reference)
//
#include <hip/hip_runtime.h>
#include <hip/hip_bf16.h>
#include <math.h>

// ---------------------------------------------------------------------------
// DGSR layer, MI355X. H = 128 fixed.
//   1. CSR build: histogram -> 3-kernel scan -> scatter of packed records
//      eu_list[pu]=int4(item,eid,ipos,0), ei_list[pi]=int2(user,eid),
//      upos[e]=pu
//   2. gemm6: fused 6 projections -> fusedU=[um_att|um_b], fusedI=[im_att|im_b],
//      last_item, last_user
//   3. dot_pv: COALESCED stream over pVui computing d1[e]=um_att[src].pVui[e],
//      scattered to d1s[user-CSR position]  (pVui's only read outside gather_i)
//   4. gather_u: 16-lane group per user (4 users/wave), serial edges with
//      unroll x2 + record prefetch. Reads fusedI + pKiu rows only.
//      Computes d0,d2,d3,d4 in-reg (4-stage shfl in 16 lanes), adds d1s[pos],
//      accumulates hLu/hSu, writes x24s[ipos]=(x2,x4).
//   5. gather_i: 16-lane group per item, reads x24s POSITIONALLY (coalesced),
//      fusedU + pVui rows, accumulates hLi/hSi. No dots, no epilogue reduce.
// pKiu read once, pVui twice (floor). exp without max-subtraction
// (logits ~N(0,1.4)). No f32 atomics anywhere.
// ---------------------------------------------------------------------------

#define WB 1024  // elements per scan block

typedef float fvec4 __attribute__((ext_vector_type(4)));

__device__ __forceinline__ float4 nt_load4(const float* p) {
    fvec4 v = __builtin_nontemporal_load((const fvec4*)p);
    return make_float4(v.x, v.y, v.z, v.w);
}
__device__ __forceinline__ float dot4(float4 a, float4 b) {
    return a.x * b.x + a.y * b.y + a.z * b.z + a.w * b.w;
}

// ----------------------- fused 6x GEMM: O[r][c] = sum_k X[g(r)][k]*W[c][k] --
struct Gemm6Desc {
    const float* X[6];
    const float* W[6];
    float*       O[6];
    const int*   g[6];
    int          ostride[6];
    int          nrows[6];
};

__global__ __launch_bounds__(256) void gemm6_kernel(Gemm6Desc d)
{
    __shared__ float Xl[64 * 32];
    __shared__ float Wl[128 * 32];
    const int j6 = blockIdx.y;
    const float* __restrict__ X = d.X[j6];
    const float* __restrict__ W = d.W[j6];
    float* __restrict__ O       = d.O[j6];
    const int* __restrict__ gidx = d.g[j6];
    const int ostride = d.ostride[j6];
    const int nrows   = d.nrows[j6];

    const int t  = threadIdx.x;
    const int tx = t & 15;
    const int ty = t >> 4;
    const int brow = blockIdx.x * 64;
    if (brow >= nrows) return;

    float acc[4][8];
#pragma unroll
    for (int j = 0; j < 4; ++j)
#pragma unroll
        for (int i = 0; i < 8; ++i) acc[j][i] = 0.f;

    for (int k0 = 0; k0 < 128; k0 += 32) {
        __syncthreads();
#pragma unroll
        for (int u = 0; u < 2; ++u) {
            int idx4 = t + u * 256;
            int r  = idx4 >> 3;
            int k4 = idx4 & 7;
            int row = brow + r;
            float4 v = make_float4(0.f, 0.f, 0.f, 0.f);
            if (row < nrows) {
                int g = gidx ? gidx[row] : row;
                v = *(const float4*)(X + (size_t)g * 128 + k0 + k4 * 4);
            }
            int sw = k4 ^ ((r >> 3) & 7);
            *(float4*)(Xl + r * 32 + sw * 4) = v;
        }
#pragma unroll
        for (int u = 0; u < 4; ++u) {
            int idx4 = t + u * 256;
            int c  = idx4 >> 3;
            int k4 = idx4 & 7;
            float4 v = *(const float4*)(W + (size_t)c * 128 + k0 + k4 * 4);
            int sw = k4 ^ ((c >> 3) & 7);
            *(float4*)(Wl + c * 32 + sw * 4) = v;
        }
        __syncthreads();
#pragma unroll
        for (int k4 = 0; k4 < 8; ++k4) {
            float4 xv[4], wv[8];
#pragma unroll
            for (int j = 0; j < 4; ++j) {
                int r = ty * 4 + j;
                xv[j] = *(const float4*)(Xl + r * 32 + ((k4 ^ ((r >> 3) & 7)) * 4));
            }
#pragma unroll
            for (int i = 0; i < 8; ++i) {
                int c = tx * 8 + i;
                wv[i] = *(const float4*)(Wl + c * 32 + ((k4 ^ ((c >> 3) & 7)) * 4));
            }
#pragma unroll
            for (int j = 0; j < 4; ++j)
#pragma unroll
                for (int i = 0; i < 8; ++i) {
                    acc[j][i] += xv[j].x * wv[i].x;
                    acc[j][i] += xv[j].y * wv[i].y;
                    acc[j][i] += xv[j].z * wv[i].z;
                    acc[j][i] += xv[j].w * wv[i].w;
                }
        }
    }
#pragma unroll
    for (int j = 0; j < 4; ++j) {
        int row = brow + ty * 4 + j;
        if (row < nrows) {
            float* op = O + (size_t)row * ostride + tx * 8;
            *(float4*)(op)     = make_float4(acc[j][0], acc[j][1], acc[j][2], acc[j][3]);
            *(float4*)(op + 4) = make_float4(acc[j][4], acc[j][5], acc[j][6], acc[j][7]);
        }
    }
}

// ----------------------- CSR build ------------------------------------------
__global__ __launch_bounds__(256) void hist_kernel(
    const int* __restrict__ ei, int E,
    int* __restrict__ deg_u, int* __restrict__ deg_i)
{
    int e = blockIdx.x * 256 + threadIdx.x;
    if (e < E) {
        atomicAdd(&deg_u[ei[e]], 1);
        atomicAdd(&deg_i[ei[E + e]], 1);
    }
}

__global__ __launch_bounds__(256) void scan_blocksums_kernel(
    const int* __restrict__ deg_u, int nu, int nbu,
    const int* __restrict__ deg_i, int ni,
    int* __restrict__ bsum)
{
    int b = blockIdx.x;
    const int* deg; int n; int base;
    if (b < nbu) { deg = deg_u; n = nu; base = b * WB; }
    else         { deg = deg_i; n = ni; base = (b - nbu) * WB; }
    int t = threadIdx.x;
    int s = 0;
#pragma unroll
    for (int j = 0; j < 4; ++j) {
        int i = base + t * 4 + j;
        if (i < n) s += deg[i];
    }
#pragma unroll
    for (int o = 32; o > 0; o >>= 1) s += __shfl_xor(s, o);
    __shared__ int wt[4];
    if ((t & 63) == 0) wt[t >> 6] = s;
    __syncthreads();
    if (t == 0) bsum[b] = wt[0] + wt[1] + wt[2] + wt[3];
}

__global__ void scan_partials_kernel(
    const int* __restrict__ bsum, int* __restrict__ bscan,
    int nbu, int nbi,
    int* __restrict__ off_u, int nu, int* __restrict__ off_i, int ni)
{
    if (threadIdx.x != 0) return;
    if (blockIdx.x == 0) {
        int c = 0;
        for (int b = 0; b < nbu; ++b) { bscan[b] = c; c += bsum[b]; }
        off_u[nu] = c;
    } else {
        int c = 0;
        for (int b = 0; b < nbi; ++b) { bscan[nbu + b] = c; c += bsum[nbu + b]; }
        off_i[ni] = c;
    }
}

__global__ __launch_bounds__(256) void scan_final_kernel(
    const int* __restrict__ deg_u, int nu, int nbu,
    const int* __restrict__ deg_i, int ni,
    const int* __restrict__ bscan,
    int* __restrict__ off_u, int* __restrict__ cur_u,
    int* __restrict__ off_i, int* __restrict__ cur_i)
{
    int b = blockIdx.x;
    const int* deg; int n; int base; int* off; int* cur;
    if (b < nbu) { deg = deg_u; n = nu; base = b * WB; off = off_u; cur = cur_u; }
    else         { deg = deg_i; n = ni; base = (b - nbu) * WB; off = off_i; cur = cur_i; }
    int t = threadIdx.x;
    int lane = t & 63, w = t >> 6;
    int v[4];
    int s = 0;
#pragma unroll
    for (int j = 0; j < 4; ++j) {
        int i = base + t * 4 + j;
        v[j] = (i < n) ? deg[i] : 0;
        s += v[j];
    }
    int inc = s;
#pragma unroll
    for (int o = 1; o < 64; o <<= 1) {
        int x = __shfl_up(inc, o);
        if (lane >= o) inc += x;
    }
    int excl = inc - s;
    __shared__ int wt[4];
    if (lane == 63) wt[w] = inc;
    __syncthreads();
    int wbase = 0;
    for (int j = 0; j < w; ++j) wbase += wt[j];
    int e = bscan[b] + wbase + excl;
#pragma unroll
    for (int j = 0; j < 4; ++j) {
        int i = base + t * 4 + j;
        if (i < n) { off[i] = e; cur[i] = e; }
        e += v[j];
    }
}

__global__ __launch_bounds__(256) void scatter_ids_kernel(
    const int* __restrict__ ei, int E,
    int* __restrict__ cur_u, int* __restrict__ cur_i,
    int4* __restrict__ eu_list, int2* __restrict__ ei_list,
    int* __restrict__ upos)
{
    int e = blockIdx.x * 256 + threadIdx.x;
    if (e < E) {
        int u = ei[e], v = ei[E + e];
        int pu = atomicAdd(&cur_u[u], 1);
        int pi = atomicAdd(&cur_i[v], 1);
        eu_list[pu] = make_int4(v, e, pi, 0);  // (item, eid, item-CSR pos)
        ei_list[pi] = make_int2(u, e);         // (user, eid)
        upos[e] = pu;
    }
}

// ----------------------- dot_pv: coalesced d1[e] = um_att[src].pVui[e] ------
__global__ __launch_bounds__(256) void dot_pv_kernel(
    const float* __restrict__ fusedU, const float* __restrict__ pVui,
    const int* __restrict__ ei, const int* __restrict__ upos, int E,
    float* __restrict__ d1s)
{
    const int wav  = (int)(((size_t)blockIdx.x * blockDim.x + threadIdx.x) >> 6);
    const int lane = threadIdx.x & 63;
    const int hw = lane >> 5, hl = lane & 31;
    const int e = wav * 2 + hw;
    if (e >= E) return;
    const int src = ei[e];
    float4 um = ((const float4*)(fusedU + (size_t)src * 256))[hl];
    float4 pv = nt_load4(pVui + (size_t)e * 128 + hl * 4);
    float d = dot4(um, pv);
#pragma unroll
    for (int o = 16; o > 0; o >>= 1) d += __shfl_xor(d, o);
    if (hl == 0) d1s[upos[e]] = d;
}

// ----------------------- gather_u: 16-lane group per user -------------------
__global__ __launch_bounds__(256) void gather_u_kernel(
    const float* __restrict__ fusedU,   // [U,256]: um_att | um_b
    const float* __restrict__ fusedI,   // [I,256]: im_att | im_b
    const float* __restrict__ last_item, const float* __restrict__ last_user,
    const float* __restrict__ pKiu,
    const int4* __restrict__ lst, const int* __restrict__ off_u,
    const float* __restrict__ d1s,
    float2* __restrict__ x24s,
    float* __restrict__ hLu, float* __restrict__ hSu, int U, float inv_sqrt_d)
{
    const int wv   = (int)(((size_t)blockIdx.x * blockDim.x + threadIdx.x) >> 6);
    const int lane = threadIdx.x & 63;
    const int g = lane >> 4;   // segment group within wave
    const int q = lane & 15;   // float4 slot
    const int uid = wv * 4 + g;
    if (uid >= U) return;

    const float4* fu4 = (const float4*)(fusedU    + (size_t)uid * 256);
    const float4* li4 = (const float4*)(last_item + (size_t)uid * 128);
    const float4* lu4 = (const float4*)(last_user + (size_t)uid * 128);
    const float4 um0 = fu4[q],      um1 = fu4[q + 16];
    const float4 li0 = li4[q],      li1 = li4[q + 16];
    const float4 lu0 = lu4[q],      lu1 = lu4[q + 16];

    float4 a1l = make_float4(0.f,0.f,0.f,0.f), a1h = make_float4(0.f,0.f,0.f,0.f);
    float4 a3l = make_float4(0.f,0.f,0.f,0.f), a3h = make_float4(0.f,0.f,0.f,0.f);
    float s1 = 0.f, s3 = 0.f;
    const int e0 = off_u[uid], e1 = off_u[uid + 1];

    int eA = e0, eB = e0 + 1;
    bool vA = eA < e1, vB = eB < e1;
    int4 rA = vA ? lst[eA] : make_int4(0, 0, 0, 0);
    int4 rB = vB ? lst[eB] : rA;
    float d1A = vA ? d1s[eA] : 0.f;
    float d1B = vB ? d1s[eB] : 0.f;

    while (vA) {
        int eA2 = eA + 2, eB2 = eB + 2;
        bool vA2 = eA2 < e1, vB2 = eB2 < e1;
        int4 rA2 = vA2 ? lst[eA2] : make_int4(0, 0, 0, 0);
        int4 rB2 = vB2 ? lst[eB2] : rA2;
        float d1A2 = vA2 ? d1s[eA2] : 0.f;
        float d1B2 = vB2 ? d1s[eB2] : 0.f;

        const float4* fIA = (const float4*)(fusedI + (size_t)rA.x * 256);
        const float*  pkA = pKiu + (size_t)rA.y * 128;
        const float4* fIB = (const float4*)(fusedI + (size_t)rB.x * 256);
        const float*  pkB = pKiu + (size_t)rB.y * 128;

        float4 iaA0 = fIA[q],      iaA1 = fIA[q + 16];
        float4 ibA0 = fIA[32 + q], ibA1 = fIA[48 + q];
        float4 pkA0 = nt_load4(pkA + q * 4), pkA1 = nt_load4(pkA + 64 + q * 4);
        float4 iaB0 = fIB[q],      iaB1 = fIB[q + 16];
        float4 ibB0 = fIB[32 + q], ibB1 = fIB[48 + q];
        float4 pkB0 = nt_load4(pkB + q * 4), pkB1 = nt_load4(pkB + 64 + q * 4);

        float dA0 = dot4(um0, iaA0) + dot4(um1, iaA1);
        float dA2 = dot4(iaA0, pkA0) + dot4(iaA1, pkA1);
        float dA3 = dot4(li0, iaA0) + dot4(li1, iaA1);
        float dA4 = dot4(lu0, iaA0) + dot4(lu1, iaA1);
        float dB0 = dot4(um0, iaB0) + dot4(um1, iaB1);
        float dB2 = dot4(iaB0, pkB0) + dot4(iaB1, pkB1);
        float dB3 = dot4(li0, iaB0) + dot4(li1, iaB1);
        float dB4 = dot4(lu0, iaB0) + dot4(lu1, iaB1);
#pragma unroll
        for (int o = 8; o > 0; o >>= 1) {
            dA0 += __shfl_xor(dA0, o); dA2 += __shfl_xor(dA2, o);
            dA3 += __shfl_xor(dA3, o); dA4 += __shfl_xor(dA4, o);
            dB0 += __shfl_xor(dB0, o); dB2 += __shfl_xor(dB2, o);
            dB3 += __shfl_xor(dB3, o); dB4 += __shfl_xor(dB4, o);
        }
        float x1A = __expf((dA0 + d1A) * inv_sqrt_d);
        float x2A = __expf((dA0 + dA2) * inv_sqrt_d);
        float x3A = __expf(dA3 * inv_sqrt_d);
        float x4A = __expf(dA4 * inv_sqrt_d);
        float mB  = vB ? 1.f : 0.f;
        float x1B = __expf((dB0 + d1B) * inv_sqrt_d) * mB;
        float x2B = __expf((dB0 + dB2) * inv_sqrt_d);
        float x3B = __expf(dB3 * inv_sqrt_d) * mB;
        float x4B = __expf(dB4 * inv_sqrt_d);

        a1l.x += x1A*(ibA0.x+pkA0.x) + x1B*(ibB0.x+pkB0.x);
        a1l.y += x1A*(ibA0.y+pkA0.y) + x1B*(ibB0.y+pkB0.y);
        a1l.z += x1A*(ibA0.z+pkA0.z) + x1B*(ibB0.z+pkB0.z);
        a1l.w += x1A*(ibA0.w+pkA0.w) + x1B*(ibB0.w+pkB0.w);
        a1h.x += x1A*(ibA1.x+pkA1.x) + x1B*(ibB1.x+pkB1.x);
        a1h.y += x1A*(ibA1.y+pkA1.y) + x1B*(ibB1.y+pkB1.y);
        a1h.z += x1A*(ibA1.z+pkA1.z) + x1B*(ibB1.z+pkB1.z);
        a1h.w += x1A*(ibA1.w+pkA1.w) + x1B*(ibB1.w+pkB1.w);
        a3l.x += x3A*(iaA0.x+1.f) + x3B*(iaB0.x+1.f);
        a3l.y += x3A*(iaA0.y+1.f) + x3B*(iaB0.y+1.f);
        a3l.z += x3A*(iaA0.z+1.f) + x3B*(iaB0.z+1.f);
        a3l.w += x3A*(iaA0.w+1.f) + x3B*(iaB0.w+1.f);
        a3h.x += x3A*(iaA1.x+1.f) + x3B*(iaB1.x+1.f);
        a3h.y += x3A*(iaA1.y+1.f) + x3B*(iaB1.y+1.f);
        a3h.z += x3A*(iaA1.z+1.f) + x3B*(iaB1.z+1.f);
        a3h.w += x3A*(iaA1.w+1.f) + x3B*(iaB1.w+1.f);
        s1 += x1A + x1B; s3 += x3A + x3B;
        if (q == 0) {
            x24s[rA.z] = make_float2(x2A, x4A);
            if (vB) x24s[rB.z] = make_float2(x2B, x4B);
        }
        eA = eA2; eB = eB2; vA = vA2; vB = vB2;
        rA = rA2; rB = rB2; d1A = d1A2; d1B = d1B2;
    }
    float r1 = (s1 > 0.f) ? 1.f / s1 : 0.f;
    float r3 = (s3 > 0.f) ? 1.f / s3 : 0.f;
    float4* oL = (float4*)(hLu + (size_t)uid * 128);
    float4* oS = (float4*)(hSu + (size_t)uid * 128);
    oL[q]      = make_float4(a1l.x*r1, a1l.y*r1, a1l.z*r1, a1l.w*r1);
    oL[q + 16] = make_float4(a1h.x*r1, a1h.y*r1, a1h.z*r1, a1h.w*r1);
    oS[q]      = make_float4(a3l.x*r3, a3l.y*r3, a3l.z*r3, a3l.w*r3);
    oS[q + 16] = make_float4(a3h.x*r3, a3h.y*r3, a3h.z*r3, a3h.w*r3);
}

// ----------------------- gather_i: 16-lane group per item -------------------
__global__ __launch_bounds__(256) void gather_i_kernel(
    const float* __restrict__ fusedU,   // [U,256]: um_att | um_b
    const float* __restrict__ pVui,
    const int2* __restrict__ lst, const int* __restrict__ off_i,
    const float2* __restrict__ x24s,
    float* __restrict__ hLi, float* __restrict__ hSi, int I)
{
    const int wv   = (int)(((size_t)blockIdx.x * blockDim.x + threadIdx.x) >> 6);
    const int lane = threadIdx.x & 63;
    const int g = lane >> 4;
    const int q = lane & 15;
    const int iid = wv * 4 + g;
    if (iid >= I) return;

    float4 a2l = make_float4(0.f,0.f,0.f,0.f), a2h = make_float4(0.f,0.f,0.f,0.f);
    float4 a4l = make_float4(0.f,0.f,0.f,0.f), a4h = make_float4(0.f,0.f,0.f,0.f);
    float s2 = 0.f, s4 = 0.f;
    const int e0 = off_i[iid], e1 = off_i[iid + 1];

    int eA = e0, eB = e0 + 1;
    bool vA = eA < e1, vB = eB < e1;
    int2 rA = vA ? lst[eA] : make_int2(0, 0);
    int2 rB = vB ? lst[eB] : rA;
    float2 xA = vA ? x24s[eA] : make_float2(0.f, 0.f);
    float2 xB = vB ? x24s[eB] : make_float2(0.f, 0.f);

    while (vA) {
        int eA2 = eA + 2, eB2 = eB + 2;
        bool vA2 = eA2 < e1, vB2 = eB2 < e1;
        int2 rA2 = vA2 ? lst[eA2] : make_int2(0, 0);
        int2 rB2 = vB2 ? lst[eB2] : rA2;
        float2 xA2v = vA2 ? x24s[eA2] : make_float2(0.f, 0.f);
        float2 xB2v = vB2 ? x24s[eB2] : make_float2(0.f, 0.f);

        const float4* fUA = (const float4*)(fusedU + (size_t)rA.x * 256);
        const float*  pvA = pVui + (size_t)rA.y * 128;
        const float4* fUB = (const float4*)(fusedU + (size_t)rB.x * 256);
        const float*  pvB = pVui + (size_t)rB.y * 128;

        float4 uaA0 = fUA[q],      uaA1 = fUA[q + 16];
        float4 ubA0 = fUA[32 + q], ubA1 = fUA[48 + q];
        float4 pvA0 = nt_load4(pvA + q * 4), pvA1 = nt_load4(pvA + 64 + q * 4);
        float4 uaB0 = fUB[q],      uaB1 = fUB[q + 16];
        float4 ubB0 = fUB[32 + q], ubB1 = fUB[48 + q];
        float4 pvB0 = nt_load4(pvB + q * 4), pvB1 = nt_load4(pvB + 64 + q * 4);

        a2l.x += xA.x*(ubA0.x+pvA0.x) + xB.x*(ubB0.x+pvB0.x);
        a2l.y += xA.x*(ubA0.y+pvA0.y) + xB.x*(ubB0.y+pvB0.y);
        a2l.z += xA.x*(ubA0.z+pvA0.z) + xB.x*(ubB0.z+pvB0.z);
        a2l.w += xA.x*(ubA0.w+pvA0.w) + xB.x*(ubB0.w+pvB0.w);
        a2h.x += xA.x*(ubA1.x+pvA1.x) + xB.x*(ubB1.x+pvB1.x);
        a2h.y += xA.x*(ubA1.y+pvA1.y) + xB.x*(ubB1.y+pvB1.y);
        a2h.z += xA.x*(ubA1.z+pvA1.z) + xB.x*(ubB1.z+pvB1.z);
        a2h.w += xA.x*(ubA1.w+pvA1.w) + xB.x*(ubB1.w+pvB1.w);
        a4l.x += xA.y*(uaA0.x+1.f) + xB.y*(uaB0.x+1.f);
        a4l.y += xA.y*(uaA0.y+1.f) + xB.y*(uaB0.y+1.f);
        a4l.z += xA.y*(uaA0.z+1.f) + xB.y*(uaB0.z+1.f);
        a4l.w += xA.y*(uaA0.w+1.f) + xB.y*(uaB0.w+1.f);
        a4h.x += xA.y*(uaA1.x+1.f) + xB.y*(uaB1.x+1.f);
        a4h.y += xA.y*(uaA1.y+1.f) + xB.y*(uaB1.y+1.f);
        a4h.z += xA.y*(uaA1.z+1.f) + xB.y*(uaB1.z+1.f);
        a4h.w += xA.y*(uaA1.w+1.f) + xB.y*(uaB1.w+1.f);
        s2 += xA.x + xB.x; s4 += xA.y + xB.y;

        eA = eA2; eB = eB2; vA = vA2; vB = vB2;
        rA = rA2; rB = rB2; xA = xA2v; xB = xB2v;
    }
    float r2 = (s2 > 0.f) ? 1.f / s2 : 0.f;
    float r4 = (s4 > 0.f) ? 1.f / s4 : 0.f;
    float4* oL = (float4*)(hLi + (size_t)iid * 128);
    float4* oS = (float4*)(hSi + (size_t)iid * 128);
    oL[q]      = make_float4(a2l.x*r2, a2l.y*r2, a2l.z*r2, a2l.w*r2);
    oL[q + 16] = make_float4(a2h.x*r2, a2h.y*r2, a2h.z*r2, a2h.w*r2);
    oS[q]      = make_float4(a4l.x*r4, a4l.y*r4, a4l.z*r4, a4l.w*r4);
    oS[q + 16] = make_float4(a4h.x*r4, a4h.y*r4, a4h.z*r4, a4h.w*r4);
}

// ---------------------------------------------------------------------------
extern "C" void kernel_launch(void* const* d_in, const int* in_sizes, int n_in,
                              void* d_out, int out_size, void* d_ws, size_t ws_size,
                              hipStream_t stream)
{
    const float* u_emb = (const float*)d_in[0];
    const float* i_emb = (const float*)d_in[1];
    const float* pVui  = (const float*)d_in[2];
    const float* pKiu  = (const float*)d_in[3];
    const float* w1    = (const float*)d_in[4];
    const float* w2    = (const float*)d_in[5];
    const float* w1b   = (const float*)d_in[6];
    const float* w2b   = (const float*)d_in[7];
    const float* w3    = (const float*)d_in[8];
    const float* w4    = (const float*)d_in[9];
    const int* edge_index = (const int*)d_in[10];
    const int* last_u     = (const int*)d_in[11];
    const int* last_i     = (const int*)d_in[12];

    const int U = in_sizes[0] / 128;
    const int I = in_sizes[1] / 128;
    const int E = in_sizes[10] / 2;
    const int nbu = (U + WB - 1) / WB;
    const int nbi = (I + WB - 1) / WB;

    float* ws = (float*)d_ws;
    float* fusedU    = ws;  ws += (size_t)U * 256;
    float* fusedI    = ws;  ws += (size_t)I * 256;
    float* last_item = ws;  ws += (size_t)U * 128;
    float* last_user = ws;  ws += (size_t)I * 128;
    float* d1s = ws;            ws += E;
    float2* x24s = (float2*)ws; ws += (size_t)E * 2;
    int4* eu_list = (int4*)ws;  ws += (size_t)E * 4;
    int2* ei_list = (int2*)ws;  ws += (size_t)E * 2;
    int* ip = (int*)ws;
    int* upos    = ip;  ip += E;
    int* deg_u   = ip;  ip += U;
    int* deg_i   = ip;  ip += I;
    int* off_u   = ip;  ip += U + 1;
    int* off_i   = ip;  ip += I + 1;
    int* cur_u   = ip;  ip += U;
    int* cur_i   = ip;  ip += I;
    int* bsum    = ip;  ip += nbu + nbi;
    int* bscan   = ip;  ip += nbu + nbi;

    float* hLu = (float*)d_out;
    float* hSu = hLu + (size_t)U * 128;
    float* hLi = hSu + (size_t)U * 128;
    float* hSi = hLi + (size_t)I * 128;

    hipMemsetAsync(deg_u, 0, (size_t)(U + I) * sizeof(int), stream);

    dim3 blk(256);
    const int eblk = (E + 255) / 256;
    hist_kernel<<<eblk, blk, 0, stream>>>(edge_index, E, deg_u, deg_i);
    scan_blocksums_kernel<<<nbu + nbi, blk, 0, stream>>>(deg_u, U, nbu, deg_i, I, bsum);
    scan_partials_kernel<<<2, 64, 0, stream>>>(bsum, bscan, nbu, nbi, off_u, U, off_i, I);
    scan_final_kernel<<<nbu + nbi, blk, 0, stream>>>(
        deg_u, U, nbu, deg_i, I, bscan, off_u, cur_u, off_i, cur_i);
    scatter_ids_kernel<<<eblk, blk, 0, stream>>>(
        edge_index, E, cur_u, cur_i, eu_list, ei_list, upos);

    Gemm6Desc gd;
    gd.X[0] = u_emb; gd.W[0] = w2;  gd.O[0] = fusedU;       gd.g[0] = nullptr;    gd.ostride[0] = 256; gd.nrows[0] = U;
    gd.X[1] = u_emb; gd.W[1] = w2b; gd.O[1] = fusedU + 128; gd.g[1] = nullptr;    gd.ostride[1] = 256; gd.nrows[1] = U;
    gd.X[2] = i_emb; gd.W[2] = w1;  gd.O[2] = fusedI;       gd.g[2] = nullptr;    gd.ostride[2] = 256; gd.nrows[2] = I;
    gd.X[3] = i_emb; gd.W[3] = w1b; gd.O[3] = fusedI + 128; gd.g[3] = nullptr;    gd.ostride[3] = 256; gd.nrows[3] = I;
    gd.X[4] = i_emb; gd.W[4] = w3;  gd.O[4] = last_item;    gd.g[4] = last_u + U; gd.ostride[4] = 128; gd.nrows[4] = U;
    gd.X[5] = u_emb; gd.W[5] = w4;  gd.O[5] = last_user;    gd.g[5] = last_i + I; gd.ostride[5] = 128; gd.nrows[5] = I;
    int maxrows = (U > I) ? U : I;
    dim3 ggrid((maxrows + 63) / 64, 6);
    gemm6_kernel<<<ggrid, blk, 0, stream>>>(gd);

    const float inv_sqrt_d = 1.0f / sqrtf(128.0f);
    dot_pv_kernel<<<(E + 7) / 8, blk, 0, stream>>>(
        fusedU, pVui, edge_index, upos, E, d1s);
    gather_u_kernel<<<(U + 15) / 16, blk, 0, stream>>>(
        fusedU, fusedI, last_item, last_user, pKiu, eu_list, off_u, d1s,
        x24s, hLu, hSu, U, inv_sqrt_d);
    gather_i_kernel<<<(I + 15) / 16, blk, 0, stream>>>(
        fusedU, pVui, ei_list, off_i, x24s, hLi, hSi, I);
}

// Round 8
// 819.792 us; speedup vs baseline: 1.1710x; 1.1710x over previous
//
#include <hip/hip_runtime.h>
#include <hip/hip_bf16.h>
#include <math.h>

// ---------------------------------------------------------------------------
// DGSR layer, MI355X. H = 128 fixed.
//   1. CSR build: histogram -> 3-kernel scan -> scatter of int2 (partner,eid)
//   2. gemm6: fused 6 projections, epilogue converts to BF16 tables:
//      fusedU=[um_att|um_b] ([U,256] bf16), fusedI=[im_att|im_b] ([I,256] bf16),
//      last_item, last_user ([.,128] bf16). Halves random-gather bytes.
//   3. gather_u: 16-lane group per user (4/wave), unroll x2 + record prefetch.
//      Reads fusedI rows (bf16) + pVui/pKiu rows (f32, nt). All 5 logit dots
//      in-reg (4 combined chains, 4-stage shfl), accumulates hLu/hSu,
//      writes x24[eid]=(x2,x4).
//   4. gather_i: 16-lane group per item, reads x24[eid], fusedU rows (bf16),
//      pVui rows (f32, nt). Pure streaming accumulate.
// exp without max-subtraction (logits ~N(0,1.4)). No f32 atomics anywhere.
// ---------------------------------------------------------------------------

#define WB 1024  // elements per scan block

typedef float fvec4 __attribute__((ext_vector_type(4)));

__device__ __forceinline__ float4 nt_load4(const float* p) {
    fvec4 v = __builtin_nontemporal_load((const fvec4*)p);
    return make_float4(v.x, v.y, v.z, v.w);
}
__device__ __forceinline__ float dot4(float4 a, float4 b) {
    return a.x * b.x + a.y * b.y + a.z * b.z + a.w * b.w;
}
// unpack 8 bf16 (uint4) -> two float4
__device__ __forceinline__ void bfu(uint4 v, float4& lo, float4& hi) {
    lo.x = __uint_as_float(v.x << 16);
    lo.y = __uint_as_float(v.x & 0xFFFF0000u);
    lo.z = __uint_as_float(v.y << 16);
    lo.w = __uint_as_float(v.y & 0xFFFF0000u);
    hi.x = __uint_as_float(v.z << 16);
    hi.y = __uint_as_float(v.z & 0xFFFF0000u);
    hi.z = __uint_as_float(v.w << 16);
    hi.w = __uint_as_float(v.w & 0xFFFF0000u);
}
__device__ __forceinline__ unsigned rne16(float f) {
    unsigned u = __float_as_uint(f);
    return (u + 0x7FFFu + ((u >> 16) & 1u)) >> 16;
}

// ----------------------- fused 6x GEMM -> bf16 tables -----------------------
struct Gemm6Desc {
    const float* X[6];
    const float* W[6];
    unsigned short* O[6];
    const int*   g[6];
    int          ostride[6];
    int          nrows[6];
};

__global__ __launch_bounds__(256) void gemm6_kernel(Gemm6Desc d)
{
    __shared__ float Xl[64 * 32];
    __shared__ float Wl[128 * 32];
    const int j6 = blockIdx.y;
    const float* __restrict__ X = d.X[j6];
    const float* __restrict__ W = d.W[j6];
    unsigned short* __restrict__ O = d.O[j6];
    const int* __restrict__ gidx = d.g[j6];
    const int ostride = d.ostride[j6];
    const int nrows   = d.nrows[j6];

    const int t  = threadIdx.x;
    const int tx = t & 15;
    const int ty = t >> 4;
    const int brow = blockIdx.x * 64;
    if (brow >= nrows) return;

    float acc[4][8];
#pragma unroll
    for (int j = 0; j < 4; ++j)
#pragma unroll
        for (int i = 0; i < 8; ++i) acc[j][i] = 0.f;

    for (int k0 = 0; k0 < 128; k0 += 32) {
        __syncthreads();
#pragma unroll
        for (int u = 0; u < 2; ++u) {
            int idx4 = t + u * 256;
            int r  = idx4 >> 3;
            int k4 = idx4 & 7;
            int row = brow + r;
            float4 v = make_float4(0.f, 0.f, 0.f, 0.f);
            if (row < nrows) {
                int g = gidx ? gidx[row] : row;
                v = *(const float4*)(X + (size_t)g * 128 + k0 + k4 * 4);
            }
            int sw = k4 ^ ((r >> 3) & 7);
            *(float4*)(Xl + r * 32 + sw * 4) = v;
        }
#pragma unroll
        for (int u = 0; u < 4; ++u) {
            int idx4 = t + u * 256;
            int c  = idx4 >> 3;
            int k4 = idx4 & 7;
            float4 v = *(const float4*)(W + (size_t)c * 128 + k0 + k4 * 4);
            int sw = k4 ^ ((c >> 3) & 7);
            *(float4*)(Wl + c * 32 + sw * 4) = v;
        }
        __syncthreads();
#pragma unroll
        for (int k4 = 0; k4 < 8; ++k4) {
            float4 xv[4], wv[8];
#pragma unroll
            for (int j = 0; j < 4; ++j) {
                int r = ty * 4 + j;
                xv[j] = *(const float4*)(Xl + r * 32 + ((k4 ^ ((r >> 3) & 7)) * 4));
            }
#pragma unroll
            for (int i = 0; i < 8; ++i) {
                int c = tx * 8 + i;
                wv[i] = *(const float4*)(Wl + c * 32 + ((k4 ^ ((c >> 3) & 7)) * 4));
            }
#pragma unroll
            for (int j = 0; j < 4; ++j)
#pragma unroll
                for (int i = 0; i < 8; ++i) {
                    acc[j][i] += xv[j].x * wv[i].x;
                    acc[j][i] += xv[j].y * wv[i].y;
                    acc[j][i] += xv[j].z * wv[i].z;
                    acc[j][i] += xv[j].w * wv[i].w;
                }
        }
    }
#pragma unroll
    for (int j = 0; j < 4; ++j) {
        int row = brow + ty * 4 + j;
        if (row < nrows) {
            unsigned short* op = O + (size_t)row * ostride + tx * 8;
            uint4 p;
            p.x = rne16(acc[j][0]) | (rne16(acc[j][1]) << 16);
            p.y = rne16(acc[j][2]) | (rne16(acc[j][3]) << 16);
            p.z = rne16(acc[j][4]) | (rne16(acc[j][5]) << 16);
            p.w = rne16(acc[j][6]) | (rne16(acc[j][7]) << 16);
            *(uint4*)op = p;
        }
    }
}

// ----------------------- CSR build ------------------------------------------
__global__ __launch_bounds__(256) void hist_kernel(
    const int* __restrict__ ei, int E,
    int* __restrict__ deg_u, int* __restrict__ deg_i)
{
    int e = blockIdx.x * 256 + threadIdx.x;
    if (e < E) {
        atomicAdd(&deg_u[ei[e]], 1);
        atomicAdd(&deg_i[ei[E + e]], 1);
    }
}

__global__ __launch_bounds__(256) void scan_blocksums_kernel(
    const int* __restrict__ deg_u, int nu, int nbu,
    const int* __restrict__ deg_i, int ni,
    int* __restrict__ bsum)
{
    int b = blockIdx.x;
    const int* deg; int n; int base;
    if (b < nbu) { deg = deg_u; n = nu; base = b * WB; }
    else         { deg = deg_i; n = ni; base = (b - nbu) * WB; }
    int t = threadIdx.x;
    int s = 0;
#pragma unroll
    for (int j = 0; j < 4; ++j) {
        int i = base + t * 4 + j;
        if (i < n) s += deg[i];
    }
#pragma unroll
    for (int o = 32; o > 0; o >>= 1) s += __shfl_xor(s, o);
    __shared__ int wt[4];
    if ((t & 63) == 0) wt[t >> 6] = s;
    __syncthreads();
    if (t == 0) bsum[b] = wt[0] + wt[1] + wt[2] + wt[3];
}

__global__ void scan_partials_kernel(
    const int* __restrict__ bsum, int* __restrict__ bscan,
    int nbu, int nbi,
    int* __restrict__ off_u, int nu, int* __restrict__ off_i, int ni)
{
    if (threadIdx.x != 0) return;
    if (blockIdx.x == 0) {
        int c = 0;
        for (int b = 0; b < nbu; ++b) { bscan[b] = c; c += bsum[b]; }
        off_u[nu] = c;
    } else {
        int c = 0;
        for (int b = 0; b < nbi; ++b) { bscan[nbu + b] = c; c += bsum[nbu + b]; }
        off_i[ni] = c;
    }
}

__global__ __launch_bounds__(256) void scan_final_kernel(
    const int* __restrict__ deg_u, int nu, int nbu,
    const int* __restrict__ deg_i, int ni,
    const int* __restrict__ bscan,
    int* __restrict__ off_u, int* __restrict__ cur_u,
    int* __restrict__ off_i, int* __restrict__ cur_i)
{
    int b = blockIdx.x;
    const int* deg; int n; int base; int* off; int* cur;
    if (b < nbu) { deg = deg_u; n = nu; base = b * WB; off = off_u; cur = cur_u; }
    else         { deg = deg_i; n = ni; base = (b - nbu) * WB; off = off_i; cur = cur_i; }
    int t = threadIdx.x;
    int lane = t & 63, w = t >> 6;
    int v[4];
    int s = 0;
#pragma unroll
    for (int j = 0; j < 4; ++j) {
        int i = base + t * 4 + j;
        v[j] = (i < n) ? deg[i] : 0;
        s += v[j];
    }
    int inc = s;
#pragma unroll
    for (int o = 1; o < 64; o <<= 1) {
        int x = __shfl_up(inc, o);
        if (lane >= o) inc += x;
    }
    int excl = inc - s;
    __shared__ int wt[4];
    if (lane == 63) wt[w] = inc;
    __syncthreads();
    int wbase = 0;
    for (int j = 0; j < w; ++j) wbase += wt[j];
    int e = bscan[b] + wbase + excl;
#pragma unroll
    for (int j = 0; j < 4; ++j) {
        int i = base + t * 4 + j;
        if (i < n) { off[i] = e; cur[i] = e; }
        e += v[j];
    }
}

__global__ __launch_bounds__(256) void scatter_ids_kernel(
    const int* __restrict__ ei, int E,
    int* __restrict__ cur_u, int* __restrict__ cur_i,
    int2* __restrict__ eu_list, int2* __restrict__ ei_list)
{
    int e = blockIdx.x * 256 + threadIdx.x;
    if (e < E) {
        int u = ei[e], v = ei[E + e];
        int pu = atomicAdd(&cur_u[u], 1);
        eu_list[pu] = make_int2(v, e);   // (item, eid)
        int pi = atomicAdd(&cur_i[v], 1);
        ei_list[pi] = make_int2(u, e);   // (user, eid)
    }
}

// ----------------------- gather_u: 16-lane group per user -------------------
__global__ __launch_bounds__(256) void gather_u_kernel(
    const unsigned short* __restrict__ fusedU,   // [U,256] bf16
    const unsigned short* __restrict__ fusedI,   // [I,256] bf16
    const unsigned short* __restrict__ last_item,
    const unsigned short* __restrict__ last_user,
    const float* __restrict__ pVui, const float* __restrict__ pKiu,
    const int2* __restrict__ lst, const int* __restrict__ off_u,
    float2* __restrict__ x24,
    float* __restrict__ hLu, float* __restrict__ hSu, int U, float inv_sqrt_d)
{
    const int wv   = (int)(((size_t)blockIdx.x * blockDim.x + threadIdx.x) >> 6);
    const int lane = threadIdx.x & 63;
    const int g = lane >> 4;   // user group within wave
    const int q = lane & 15;   // 8-element slot within row
    const int uid = wv * 4 + g;
    if (uid >= U) return;

    float4 um0, um1, li0, li1, lu0, lu1;
    bfu(((const uint4*)(fusedU    + (size_t)uid * 256))[q], um0, um1);
    bfu(((const uint4*)(last_item + (size_t)uid * 128))[q], li0, li1);
    bfu(((const uint4*)(last_user + (size_t)uid * 128))[q], lu0, lu1);

    float4 a1l = make_float4(0.f,0.f,0.f,0.f), a1h = make_float4(0.f,0.f,0.f,0.f);
    float4 a3l = make_float4(0.f,0.f,0.f,0.f), a3h = make_float4(0.f,0.f,0.f,0.f);
    float s1 = 0.f, s3 = 0.f;
    const int e0 = off_u[uid], e1 = off_u[uid + 1];

    int eA = e0, eB = e0 + 1;
    bool vA = eA < e1, vB = eB < e1;
    int2 rA = vA ? lst[eA] : make_int2(0, 0);
    int2 rB = vB ? lst[eB] : rA;

    while (vA) {
        int eA2 = eA + 2, eB2 = eB + 2;
        bool vA2 = eA2 < e1, vB2 = eB2 < e1;
        int2 rA2 = vA2 ? lst[eA2] : make_int2(0, 0);
        int2 rB2 = vB2 ? lst[eB2] : rA2;

        const uint4* fIA = (const uint4*)(fusedI + (size_t)rA.x * 256);
        const float* pvA = pVui + (size_t)rA.y * 128 + q * 8;
        const float* pkA = pKiu + (size_t)rA.y * 128 + q * 8;
        const uint4* fIB = (const uint4*)(fusedI + (size_t)rB.x * 256);
        const float* pvB = pVui + (size_t)rB.y * 128 + q * 8;
        const float* pkB = pKiu + (size_t)rB.y * 128 + q * 8;

        uint4 iaAp = fIA[q], ibAp = fIA[16 + q];
        uint4 iaBp = fIB[q], ibBp = fIB[16 + q];
        float4 pvA0 = nt_load4(pvA), pvA1 = nt_load4(pvA + 4);
        float4 pkA0 = nt_load4(pkA), pkA1 = nt_load4(pkA + 4);
        float4 pvB0 = nt_load4(pvB), pvB1 = nt_load4(pvB + 4);
        float4 pkB0 = nt_load4(pkB), pkB1 = nt_load4(pkB + 4);

        float4 iaA0, iaA1, ibA0, ibA1, iaB0, iaB1, ibB0, ibB1;
        bfu(iaAp, iaA0, iaA1); bfu(ibAp, ibA0, ibA1);
        bfu(iaBp, iaB0, iaB1); bfu(ibBp, ibB0, ibB1);

        float dA0 = dot4(um0, iaA0) + dot4(um1, iaA1);
        float qA1 = dA0 + dot4(um0, pvA0) + dot4(um1, pvA1);
        float qA2 = dA0 + dot4(iaA0, pkA0) + dot4(iaA1, pkA1);
        float qA3 = dot4(li0, iaA0) + dot4(li1, iaA1);
        float qA4 = dot4(lu0, iaA0) + dot4(lu1, iaA1);
        float dB0 = dot4(um0, iaB0) + dot4(um1, iaB1);
        float qB1 = dB0 + dot4(um0, pvB0) + dot4(um1, pvB1);
        float qB2 = dB0 + dot4(iaB0, pkB0) + dot4(iaB1, pkB1);
        float qB3 = dot4(li0, iaB0) + dot4(li1, iaB1);
        float qB4 = dot4(lu0, iaB0) + dot4(lu1, iaB1);
#pragma unroll
        for (int o = 8; o > 0; o >>= 1) {
            qA1 += __shfl_xor(qA1, o); qA2 += __shfl_xor(qA2, o);
            qA3 += __shfl_xor(qA3, o); qA4 += __shfl_xor(qA4, o);
            qB1 += __shfl_xor(qB1, o); qB2 += __shfl_xor(qB2, o);
            qB3 += __shfl_xor(qB3, o); qB4 += __shfl_xor(qB4, o);
        }
        float x1A = __expf(qA1 * inv_sqrt_d);
        float x2A = __expf(qA2 * inv_sqrt_d);
        float x3A = __expf(qA3 * inv_sqrt_d);
        float x4A = __expf(qA4 * inv_sqrt_d);
        float mB  = vB ? 1.f : 0.f;
        float x1B = __expf(qB1 * inv_sqrt_d) * mB;
        float x2B = __expf(qB2 * inv_sqrt_d);
        float x3B = __expf(qB3 * inv_sqrt_d) * mB;
        float x4B = __expf(qB4 * inv_sqrt_d);

        a1l.x += x1A*(ibA0.x+pkA0.x) + x1B*(ibB0.x+pkB0.x);
        a1l.y += x1A*(ibA0.y+pkA0.y) + x1B*(ibB0.y+pkB0.y);
        a1l.z += x1A*(ibA0.z+pkA0.z) + x1B*(ibB0.z+pkB0.z);
        a1l.w += x1A*(ibA0.w+pkA0.w) + x1B*(ibB0.w+pkB0.w);
        a1h.x += x1A*(ibA1.x+pkA1.x) + x1B*(ibB1.x+pkB1.x);
        a1h.y += x1A*(ibA1.y+pkA1.y) + x1B*(ibB1.y+pkB1.y);
        a1h.z += x1A*(ibA1.z+pkA1.z) + x1B*(ibB1.z+pkB1.z);
        a1h.w += x1A*(ibA1.w+pkA1.w) + x1B*(ibB1.w+pkB1.w);
        a3l.x += x3A*(iaA0.x+1.f) + x3B*(iaB0.x+1.f);
        a3l.y += x3A*(iaA0.y+1.f) + x3B*(iaB0.y+1.f);
        a3l.z += x3A*(iaA0.z+1.f) + x3B*(iaB0.z+1.f);
        a3l.w += x3A*(iaA0.w+1.f) + x3B*(iaB0.w+1.f);
        a3h.x += x3A*(iaA1.x+1.f) + x3B*(iaB1.x+1.f);
        a3h.y += x3A*(iaA1.y+1.f) + x3B*(iaB1.y+1.f);
        a3h.z += x3A*(iaA1.z+1.f) + x3B*(iaB1.z+1.f);
        a3h.w += x3A*(iaA1.w+1.f) + x3B*(iaB1.w+1.f);
        s1 += x1A + x1B; s3 += x3A + x3B;
        if (q == 0) {
            x24[rA.y] = make_float2(x2A, x4A);
            if (vB) x24[rB.y] = make_float2(x2B, x4B);
        }
        eA = eA2; eB = eB2; vA = vA2; vB = vB2; rA = rA2; rB = rB2;
    }
    float r1 = (s1 > 0.f) ? 1.f / s1 : 0.f;
    float r3 = (s3 > 0.f) ? 1.f / s3 : 0.f;
    float4* oL = (float4*)(hLu + (size_t)uid * 128);
    float4* oS = (float4*)(hSu + (size_t)uid * 128);
    oL[2*q]     = make_float4(a1l.x*r1, a1l.y*r1, a1l.z*r1, a1l.w*r1);
    oL[2*q + 1] = make_float4(a1h.x*r1, a1h.y*r1, a1h.z*r1, a1h.w*r1);
    oS[2*q]     = make_float4(a3l.x*r3, a3l.y*r3, a3l.z*r3, a3l.w*r3);
    oS[2*q + 1] = make_float4(a3h.x*r3, a3h.y*r3, a3h.z*r3, a3h.w*r3);
}

// ----------------------- gather_i: 16-lane group per item -------------------
__global__ __launch_bounds__(256) void gather_i_kernel(
    const unsigned short* __restrict__ fusedU,   // [U,256] bf16
    const float* __restrict__ pVui,
    const int2* __restrict__ lst, const int* __restrict__ off_i,
    const float2* __restrict__ x24,
    float* __restrict__ hLi, float* __restrict__ hSi, int I)
{
    const int wv   = (int)(((size_t)blockIdx.x * blockDim.x + threadIdx.x) >> 6);
    const int lane = threadIdx.x & 63;
    const int g = lane >> 4;
    const int q = lane & 15;
    const int iid = wv * 4 + g;
    if (iid >= I) return;

    float4 a2l = make_float4(0.f,0.f,0.f,0.f), a2h = make_float4(0.f,0.f,0.f,0.f);
    float4 a4l = make_float4(0.f,0.f,0.f,0.f), a4h = make_float4(0.f,0.f,0.f,0.f);
    float s2 = 0.f, s4 = 0.f;
    const int e0 = off_i[iid], e1 = off_i[iid + 1];

    int eA = e0, eB = e0 + 1;
    bool vA = eA < e1, vB = eB < e1;
    int2 rA = vA ? lst[eA] : make_int2(0, 0);
    int2 rB = vB ? lst[eB] : rA;
    float2 xA = vA ? x24[rA.y] : make_float2(0.f, 0.f);
    float2 xB = vB ? x24[rB.y] : make_float2(0.f, 0.f);

    while (vA) {
        int eA2 = eA + 2, eB2 = eB + 2;
        bool vA2 = eA2 < e1, vB2 = eB2 < e1;
        int2 rA2 = vA2 ? lst[eA2] : make_int2(0, 0);
        int2 rB2 = vB2 ? lst[eB2] : rA2;
        float2 xA2v = vA2 ? x24[rA2.y] : make_float2(0.f, 0.f);
        float2 xB2v = vB2 ? x24[rB2.y] : make_float2(0.f, 0.f);

        const uint4* fUA = (const uint4*)(fusedU + (size_t)rA.x * 256);
        const float* pvA = pVui + (size_t)rA.y * 128 + q * 8;
        const uint4* fUB = (const uint4*)(fusedU + (size_t)rB.x * 256);
        const float* pvB = pVui + (size_t)rB.y * 128 + q * 8;

        uint4 uaAp = fUA[q], ubAp = fUA[16 + q];
        uint4 uaBp = fUB[q], ubBp = fUB[16 + q];
        float4 pvA0 = nt_load4(pvA), pvA1 = nt_load4(pvA + 4);
        float4 pvB0 = nt_load4(pvB), pvB1 = nt_load4(pvB + 4);

        float4 uaA0, uaA1, ubA0, ubA1, uaB0, uaB1, ubB0, ubB1;
        bfu(uaAp, uaA0, uaA1); bfu(ubAp, ubA0, ubA1);
        bfu(uaBp, uaB0, uaB1); bfu(ubBp, ubB0, ubB1);

        if (!vB) { xB.x = 0.f; xB.y = 0.f; }
        a2l.x += xA.x*(ubA0.x+pvA0.x) + xB.x*(ubB0.x+pvB0.x);
        a2l.y += xA.x*(ubA0.y+pvA0.y) + xB.x*(ubB0.y+pvB0.y);
        a2l.z += xA.x*(ubA0.z+pvA0.z) + xB.x*(ubB0.z+pvB0.z);
        a2l.w += xA.x*(ubA0.w+pvA0.w) + xB.x*(ubB0.w+pvB0.w);
        a2h.x += xA.x*(ubA1.x+pvA1.x) + xB.x*(ubB1.x+pvB1.x);
        a2h.y += xA.x*(ubA1.y+pvA1.y) + xB.x*(ubB1.y+pvB1.y);
        a2h.z += xA.x*(ubA1.z+pvA1.z) + xB.x*(ubB1.z+pvB1.z);
        a2h.w += xA.x*(ubA1.w+pvA1.w) + xB.x*(ubB1.w+pvB1.w);
        a4l.x += xA.y*(uaA0.x+1.f) + xB.y*(uaB0.x+1.f);
        a4l.y += xA.y*(uaA0.y+1.f) + xB.y*(uaB0.y+1.f);
        a4l.z += xA.y*(uaA0.z+1.f) + xB.y*(uaB0.z+1.f);
        a4l.w += xA.y*(uaA0.w+1.f) + xB.y*(uaB0.w+1.f);
        a4h.x += xA.y*(uaA1.x+1.f) + xB.y*(uaB1.x+1.f);
        a4h.y += xA.y*(uaA1.y+1.f) + xB.y*(uaB1.y+1.f);
        a4h.z += xA.y*(uaA1.z+1.f) + xB.y*(uaB1.z+1.f);
        a4h.w += xA.y*(uaA1.w+1.f) + xB.y*(uaB1.w+1.f);
        s2 += xA.x + xB.x; s4 += xA.y + xB.y;

        eA = eA2; eB = eB2; vA = vA2; vB = vB2;
        rA = rA2; rB = rB2; xA = xA2v; xB = xB2v;
    }
    float r2 = (s2 > 0.f) ? 1.f / s2 : 0.f;
    float r4 = (s4 > 0.f) ? 1.f / s4 : 0.f;
    float4* oL = (float4*)(hLi + (size_t)iid * 128);
    float4* oS = (float4*)(hSi + (size_t)iid * 128);
    oL[2*q]     = make_float4(a2l.x*r2, a2l.y*r2, a2l.z*r2, a2l.w*r2);
    oL[2*q + 1] = make_float4(a2h.x*r2, a2h.y*r2, a2h.z*r2, a2h.w*r2);
    oS[2*q]     = make_float4(a4l.x*r4, a4l.y*r4, a4l.z*r4, a4l.w*r4);
    oS[2*q + 1] = make_float4(a4h.x*r4, a4h.y*r4, a4h.z*r4, a4h.w*r4);
}

// ---------------------------------------------------------------------------
extern "C" void kernel_launch(void* const* d_in, const int* in_sizes, int n_in,
                              void* d_out, int out_size, void* d_ws, size_t ws_size,
                              hipStream_t stream)
{
    const float* u_emb = (const float*)d_in[0];
    const float* i_emb = (const float*)d_in[1];
    const float* pVui  = (const float*)d_in[2];
    const float* pKiu  = (const float*)d_in[3];
    const float* w1    = (const float*)d_in[4];
    const float* w2    = (const float*)d_in[5];
    const float* w1b   = (const float*)d_in[6];
    const float* w2b   = (const float*)d_in[7];
    const float* w3    = (const float*)d_in[8];
    const float* w4    = (const float*)d_in[9];
    const int* edge_index = (const int*)d_in[10];
    const int* last_u     = (const int*)d_in[11];
    const int* last_i     = (const int*)d_in[12];

    const int U = in_sizes[0] / 128;
    const int I = in_sizes[1] / 128;
    const int E = in_sizes[10] / 2;
    const int nbu = (U + WB - 1) / WB;
    const int nbi = (I + WB - 1) / WB;

    unsigned short* us = (unsigned short*)d_ws;
    unsigned short* fusedU    = us;  us += (size_t)U * 256;
    unsigned short* fusedI    = us;  us += (size_t)I * 256;
    unsigned short* last_item = us;  us += (size_t)U * 128;
    unsigned short* last_user = us;  us += (size_t)I * 128;
    float* ws = (float*)us;
    float2* x24 = (float2*)ws;  ws += (size_t)E * 2;
    int2* eu_list = (int2*)ws;  ws += (size_t)E * 2;
    int2* ei_list = (int2*)ws;  ws += (size_t)E * 2;
    int* ip = (int*)ws;
    int* deg_u   = ip;  ip += U;
    int* deg_i   = ip;  ip += I;
    int* off_u   = ip;  ip += U + 1;
    int* off_i   = ip;  ip += I + 1;
    int* cur_u   = ip;  ip += U;
    int* cur_i   = ip;  ip += I;
    int* bsum    = ip;  ip += nbu + nbi;
    int* bscan   = ip;  ip += nbu + nbi;

    float* hLu = (float*)d_out;
    float* hSu = hLu + (size_t)U * 128;
    float* hLi = hSu + (size_t)U * 128;
    float* hSi = hLi + (size_t)I * 128;

    hipMemsetAsync(deg_u, 0, (size_t)(U + I) * sizeof(int), stream);

    dim3 blk(256);
    const int eblk = (E + 255) / 256;
    hist_kernel<<<eblk, blk, 0, stream>>>(edge_index, E, deg_u, deg_i);
    scan_blocksums_kernel<<<nbu + nbi, blk, 0, stream>>>(deg_u, U, nbu, deg_i, I, bsum);
    scan_partials_kernel<<<2, 64, 0, stream>>>(bsum, bscan, nbu, nbi, off_u, U, off_i, I);
    scan_final_kernel<<<nbu + nbi, blk, 0, stream>>>(
        deg_u, U, nbu, deg_i, I, bscan, off_u, cur_u, off_i, cur_i);
    scatter_ids_kernel<<<eblk, blk, 0, stream>>>(
        edge_index, E, cur_u, cur_i, eu_list, ei_list);

    Gemm6Desc gd;
    gd.X[0] = u_emb; gd.W[0] = w2;  gd.O[0] = fusedU;       gd.g[0] = nullptr;    gd.ostride[0] = 256; gd.nrows[0] = U;
    gd.X[1] = u_emb; gd.W[1] = w2b; gd.O[1] = fusedU + 128; gd.g[1] = nullptr;    gd.ostride[1] = 256; gd.nrows[1] = U;
    gd.X[2] = i_emb; gd.W[2] = w1;  gd.O[2] = fusedI;       gd.g[2] = nullptr;    gd.ostride[2] = 256; gd.nrows[2] = I;
    gd.X[3] = i_emb; gd.W[3] = w1b; gd.O[3] = fusedI + 128; gd.g[3] = nullptr;    gd.ostride[3] = 256; gd.nrows[3] = I;
    gd.X[4] = i_emb; gd.W[4] = w3;  gd.O[4] = last_item;    gd.g[4] = last_u + U; gd.ostride[4] = 128; gd.nrows[4] = U;
    gd.X[5] = u_emb; gd.W[5] = w4;  gd.O[5] = last_user;    gd.g[5] = last_i + I; gd.ostride[5] = 128; gd.nrows[5] = I;
    int maxrows = (U > I) ? U : I;
    dim3 ggrid((maxrows + 63) / 64, 6);
    gemm6_kernel<<<ggrid, blk, 0, stream>>>(gd);

    const float inv_sqrt_d = 1.0f / sqrtf(128.0f);
    gather_u_kernel<<<(U + 15) / 16, blk, 0, stream>>>(
        fusedU, fusedI, last_item, last_user, pVui, pKiu, eu_list, off_u,
        x24, hLu, hSu, U, inv_sqrt_d);
    gather_i_kernel<<<(I + 15) / 16, blk, 0, stream>>>(
        fusedU, pVui, ei_list, off_i, x24, hLi, hSi, I);
}

// Round 10
// 711.136 us; speedup vs baseline: 1.3499x; 1.1528x over previous
//
#include <hip/hip_runtime.h>
#include <hip/hip_bf16.h>
#include <math.h>

// ---------------------------------------------------------------------------
// DGSR layer, MI355X. H = 128 fixed.
//   1. CSR build: histogram -> 3-kernel scan -> scatter of int2 (partner,eid)
//   2. gemm6: fused 6 projections, epilogue writes BF16 tables in an
//      INTERLEAVED layout: each 128-col block stored as 16 x 16B chunks,
//      chunk q = {elems 4q..4q+3, elems 64+4q..64+4q+3}. A single uint4
//      load per lane is contiguous AND matches the f32 p-row layout
//      (float4 at [4q] and [64+4q] -> two contiguous 256B segments).
//   3. gather_u: 16-lane group per user (4/wave), unroll x2 + record
//      prefetch. All 5 logit dots in-reg (4 chains, 4-stage shfl),
//      accumulates hLu/hSu, writes x24[eid]=(x2,x4).
//   4. gather_i: 16-lane group per item, pure streaming accumulate.
// exp without max-subtraction (logits ~N(0,1.4)). No f32 atomics anywhere.
// ---------------------------------------------------------------------------

#define WB 1024  // elements per scan block

typedef float fvec4 __attribute__((ext_vector_type(4)));

__device__ __forceinline__ float4 nt_load4(const float* p) {
    fvec4 v = __builtin_nontemporal_load((const fvec4*)p);
    return make_float4(v.x, v.y, v.z, v.w);
}
__device__ __forceinline__ float dot4(float4 a, float4 b) {
    return a.x * b.x + a.y * b.y + a.z * b.z + a.w * b.w;
}
// unpack 8 bf16 (uint4 = one interleaved chunk) -> lo4 (elems 4q..) hi4 (64+4q..)
__device__ __forceinline__ void bfu(uint4 v, float4& lo, float4& hi) {
    lo.x = __uint_as_float(v.x << 16);
    lo.y = __uint_as_float(v.x & 0xFFFF0000u);
    lo.z = __uint_as_float(v.y << 16);
    lo.w = __uint_as_float(v.y & 0xFFFF0000u);
    hi.x = __uint_as_float(v.z << 16);
    hi.y = __uint_as_float(v.z & 0xFFFF0000u);
    hi.z = __uint_as_float(v.w << 16);
    hi.w = __uint_as_float(v.w & 0xFFFF0000u);
}
__device__ __forceinline__ unsigned rne16(float f) {
    unsigned u = __float_as_uint(f);
    return (u + 0x7FFFu + ((u >> 16) & 1u)) >> 16;
}
__device__ __forceinline__ unsigned pack2(float a, float b) {
    return rne16(a) | (rne16(b) << 16);
}

// ----------------------- fused 6x GEMM -> interleaved bf16 tables -----------
struct Gemm6Desc {
    const float* X[6];
    const float* W[6];
    unsigned short* O[6];
    const int*   g[6];
    int          ostride[6];
    int          nrows[6];
};

__global__ __launch_bounds__(256) void gemm6_kernel(Gemm6Desc d)
{
    __shared__ float Xl[64 * 32];
    __shared__ float Wl[128 * 32];
    const int j6 = blockIdx.y;
    const float* __restrict__ X = d.X[j6];
    const float* __restrict__ W = d.W[j6];
    unsigned short* __restrict__ O = d.O[j6];
    const int* __restrict__ gidx = d.g[j6];
    const int ostride = d.ostride[j6];
    const int nrows   = d.nrows[j6];

    const int t  = threadIdx.x;
    const int tx = t & 15;
    const int ty = t >> 4;
    const int brow = blockIdx.x * 64;
    if (brow >= nrows) return;

    float acc[4][8];
#pragma unroll
    for (int j = 0; j < 4; ++j)
#pragma unroll
        for (int i = 0; i < 8; ++i) acc[j][i] = 0.f;

    for (int k0 = 0; k0 < 128; k0 += 32) {
        __syncthreads();
#pragma unroll
        for (int u = 0; u < 2; ++u) {
            int idx4 = t + u * 256;
            int r  = idx4 >> 3;
            int k4 = idx4 & 7;
            int row = brow + r;
            float4 v = make_float4(0.f, 0.f, 0.f, 0.f);
            if (row < nrows) {
                int g = gidx ? gidx[row] : row;
                v = *(const float4*)(X + (size_t)g * 128 + k0 + k4 * 4);
            }
            int sw = k4 ^ ((r >> 3) & 7);
            *(float4*)(Xl + r * 32 + sw * 4) = v;
        }
#pragma unroll
        for (int u = 0; u < 4; ++u) {
            int idx4 = t + u * 256;
            int c  = idx4 >> 3;
            int k4 = idx4 & 7;
            float4 v = *(const float4*)(W + (size_t)c * 128 + k0 + k4 * 4);
            int sw = k4 ^ ((c >> 3) & 7);
            *(float4*)(Wl + c * 32 + sw * 4) = v;
        }
        __syncthreads();
#pragma unroll
        for (int k4 = 0; k4 < 8; ++k4) {
            float4 xv[4], wv[8];
#pragma unroll
            for (int j = 0; j < 4; ++j) {
                int r = ty * 4 + j;
                xv[j] = *(const float4*)(Xl + r * 32 + ((k4 ^ ((r >> 3) & 7)) * 4));
            }
#pragma unroll
            for (int i = 0; i < 8; ++i) {
                int c = tx * 8 + i;
                wv[i] = *(const float4*)(Wl + c * 32 + ((k4 ^ ((c >> 3) & 7)) * 4));
            }
#pragma unroll
            for (int j = 0; j < 4; ++j)
#pragma unroll
                for (int i = 0; i < 8; ++i) {
                    acc[j][i] += xv[j].x * wv[i].x;
                    acc[j][i] += xv[j].y * wv[i].y;
                    acc[j][i] += xv[j].z * wv[i].z;
                    acc[j][i] += xv[j].w * wv[i].w;
                }
        }
    }
    // interleaved epilogue: cols 8tx..8tx+3 and 8tx+4..8tx+7 go to the lo
    // (tx<8) or hi (tx>=8) 8B halves of chunks 2tx(') and 2tx(')+1.
    const int base = (tx < 8) ? (16 * tx) : (16 * (tx - 8) + 4);
#pragma unroll
    for (int j = 0; j < 4; ++j) {
        int row = brow + ty * 4 + j;
        if (row < nrows) {
            unsigned short* op = O + (size_t)row * ostride;
            uint2 lo, hi;
            lo.x = pack2(acc[j][0], acc[j][1]);
            lo.y = pack2(acc[j][2], acc[j][3]);
            hi.x = pack2(acc[j][4], acc[j][5]);
            hi.y = pack2(acc[j][6], acc[j][7]);
            *(uint2*)(op + base)     = lo;
            *(uint2*)(op + base + 8) = hi;
        }
    }
}

// ----------------------- CSR build ------------------------------------------
__global__ __launch_bounds__(256) void hist_kernel(
    const int* __restrict__ ei, int E,
    int* __restrict__ deg_u, int* __restrict__ deg_i)
{
    int e = blockIdx.x * 256 + threadIdx.x;
    if (e < E) {
        atomicAdd(&deg_u[ei[e]], 1);
        atomicAdd(&deg_i[ei[E + e]], 1);
    }
}

__global__ __launch_bounds__(256) void scan_blocksums_kernel(
    const int* __restrict__ deg_u, int nu, int nbu,
    const int* __restrict__ deg_i, int ni,
    int* __restrict__ bsum)
{
    int b = blockIdx.x;
    const int* deg; int n; int base;
    if (b < nbu) { deg = deg_u; n = nu; base = b * WB; }
    else         { deg = deg_i; n = ni; base = (b - nbu) * WB; }
    int t = threadIdx.x;
    int s = 0;
#pragma unroll
    for (int j = 0; j < 4; ++j) {
        int i = base + t * 4 + j;
        if (i < n) s += deg[i];
    }
#pragma unroll
    for (int o = 32; o > 0; o >>= 1) s += __shfl_xor(s, o);
    __shared__ int wt[4];
    if ((t & 63) == 0) wt[t >> 6] = s;
    __syncthreads();
    if (t == 0) bsum[b] = wt[0] + wt[1] + wt[2] + wt[3];
}

__global__ void scan_partials_kernel(
    const int* __restrict__ bsum, int* __restrict__ bscan,
    int nbu, int nbi,
    int* __restrict__ off_u, int nu, int* __restrict__ off_i, int ni)
{
    if (threadIdx.x != 0) return;
    if (blockIdx.x == 0) {
        int c = 0;
        for (int b = 0; b < nbu; ++b) { bscan[b] = c; c += bsum[b]; }
        off_u[nu] = c;
    } else {
        int c = 0;
        for (int b = 0; b < nbi; ++b) { bscan[nbu + b] = c; c += bsum[nbu + b]; }
        off_i[ni] = c;
    }
}

__global__ __launch_bounds__(256) void scan_final_kernel(
    const int* __restrict__ deg_u, int nu, int nbu,
    const int* __restrict__ deg_i, int ni,
    const int* __restrict__ bscan,
    int* __restrict__ off_u, int* __restrict__ cur_u,
    int* __restrict__ off_i, int* __restrict__ cur_i)
{
    int b = blockIdx.x;
    const int* deg; int n; int base; int* off; int* cur;
    if (b < nbu) { deg = deg_u; n = nu; base = b * WB; off = off_u; cur = cur_u; }
    else         { deg = deg_i; n = ni; base = (b - nbu) * WB; off = off_i; cur = cur_i; }
    int t = threadIdx.x;
    int lane = t & 63, w = t >> 6;
    int v[4];
    int s = 0;
#pragma unroll
    for (int j = 0; j < 4; ++j) {
        int i = base + t * 4 + j;
        v[j] = (i < n) ? deg[i] : 0;
        s += v[j];
    }
    int inc = s;
#pragma unroll
    for (int o = 1; o < 64; o <<= 1) {
        int x = __shfl_up(inc, o);
        if (lane >= o) inc += x;
    }
    int excl = inc - s;
    __shared__ int wt[4];
    if (lane == 63) wt[w] = inc;
    __syncthreads();
    int wbase = 0;
    for (int j = 0; j < w; ++j) wbase += wt[j];
    int e = bscan[b] + wbase + excl;
#pragma unroll
    for (int j = 0; j < 4; ++j) {
        int i = base + t * 4 + j;
        if (i < n) { off[i] = e; cur[i] = e; }
        e += v[j];
    }
}

__global__ __launch_bounds__(256) void scatter_ids_kernel(
    const int* __restrict__ ei, int E,
    int* __restrict__ cur_u, int* __restrict__ cur_i,
    int2* __restrict__ eu_list, int2* __restrict__ ei_list)
{
    int e = blockIdx.x * 256 + threadIdx.x;
    if (e < E) {
        int u = ei[e], v = ei[E + e];
        int pu = atomicAdd(&cur_u[u], 1);
        eu_list[pu] = make_int2(v, e);   // (item, eid)
        int pi = atomicAdd(&cur_i[v], 1);
        ei_list[pi] = make_int2(u, e);   // (user, eid)
    }
}

// ----------------------- gather_u: 16-lane group per user -------------------
__global__ __launch_bounds__(256) void gather_u_kernel(
    const unsigned short* __restrict__ fusedU,   // [U,256] bf16 interleaved
    const unsigned short* __restrict__ fusedI,   // [I,256] bf16 interleaved
    const unsigned short* __restrict__ last_item,
    const unsigned short* __restrict__ last_user,
    const float* __restrict__ pVui, const float* __restrict__ pKiu,
    const int2* __restrict__ lst, const int* __restrict__ off_u,
    float2* __restrict__ x24,
    float* __restrict__ hLu, float* __restrict__ hSu, int U, float inv_sqrt_d)
{
    const int wv   = (int)(((size_t)blockIdx.x * blockDim.x + threadIdx.x) >> 6);
    const int lane = threadIdx.x & 63;
    const int g = lane >> 4;   // user group within wave
    const int q = lane & 15;   // chunk slot: elems {4q..4q+3, 64+4q..64+4q+3}
    const int uid = wv * 4 + g;
    if (uid >= U) return;

    float4 um0, um1, li0, li1, lu0, lu1;
    bfu(((const uint4*)(fusedU    + (size_t)uid * 256))[q], um0, um1);
    bfu(((const uint4*)(last_item + (size_t)uid * 128))[q], li0, li1);
    bfu(((const uint4*)(last_user + (size_t)uid * 128))[q], lu0, lu1);

    float4 a1l = make_float4(0.f,0.f,0.f,0.f), a1h = make_float4(0.f,0.f,0.f,0.f);
    float4 a3l = make_float4(0.f,0.f,0.f,0.f), a3h = make_float4(0.f,0.f,0.f,0.f);
    float s1 = 0.f, s3 = 0.f;
    const int e0 = off_u[uid], e1 = off_u[uid + 1];

    int eA = e0, eB = e0 + 1;
    bool vA = eA < e1, vB = eB < e1;
    int2 rA = vA ? lst[eA] : make_int2(0, 0);
    int2 rB = vB ? lst[eB] : rA;

    while (vA) {
        int eA2 = eA + 2, eB2 = eB + 2;
        bool vA2 = eA2 < e1, vB2 = eB2 < e1;
        int2 rA2 = vA2 ? lst[eA2] : make_int2(0, 0);
        int2 rB2 = vB2 ? lst[eB2] : rA2;

        const uint4* fIA = (const uint4*)(fusedI + (size_t)rA.x * 256);
        const float* pvA = pVui + (size_t)rA.y * 128;
        const float* pkA = pKiu + (size_t)rA.y * 128;
        const uint4* fIB = (const uint4*)(fusedI + (size_t)rB.x * 256);
        const float* pvB = pVui + (size_t)rB.y * 128;
        const float* pkB = pKiu + (size_t)rB.y * 128;

        uint4 iaAp = fIA[q], ibAp = fIA[16 + q];
        uint4 iaBp = fIB[q], ibBp = fIB[16 + q];
        float4 pvA0 = nt_load4(pvA + q * 4), pvA1 = nt_load4(pvA + 64 + q * 4);
        float4 pkA0 = nt_load4(pkA + q * 4), pkA1 = nt_load4(pkA + 64 + q * 4);
        float4 pvB0 = nt_load4(pvB + q * 4), pvB1 = nt_load4(pvB + 64 + q * 4);
        float4 pkB0 = nt_load4(pkB + q * 4), pkB1 = nt_load4(pkB + 64 + q * 4);

        float4 iaA0, iaA1, ibA0, ibA1, iaB0, iaB1, ibB0, ibB1;
        bfu(iaAp, iaA0, iaA1); bfu(ibAp, ibA0, ibA1);
        bfu(iaBp, iaB0, iaB1); bfu(ibBp, ibB0, ibB1);

        float dA0 = dot4(um0, iaA0) + dot4(um1, iaA1);
        float qA1 = dA0 + dot4(um0, pvA0) + dot4(um1, pvA1);
        float qA2 = dA0 + dot4(iaA0, pkA0) + dot4(iaA1, pkA1);
        float qA3 = dot4(li0, iaA0) + dot4(li1, iaA1);
        float qA4 = dot4(lu0, iaA0) + dot4(lu1, iaA1);
        float dB0 = dot4(um0, iaB0) + dot4(um1, iaB1);
        float qB1 = dB0 + dot4(um0, pvB0) + dot4(um1, pvB1);
        float qB2 = dB0 + dot4(iaB0, pkB0) + dot4(iaB1, pkB1);
        float qB3 = dot4(li0, iaB0) + dot4(li1, iaB1);
        float qB4 = dot4(lu0, iaB0) + dot4(lu1, iaB1);
#pragma unroll
        for (int o = 8; o > 0; o >>= 1) {
            qA1 += __shfl_xor(qA1, o); qA2 += __shfl_xor(qA2, o);
            qA3 += __shfl_xor(qA3, o); qA4 += __shfl_xor(qA4, o);
            qB1 += __shfl_xor(qB1, o); qB2 += __shfl_xor(qB2, o);
            qB3 += __shfl_xor(qB3, o); qB4 += __shfl_xor(qB4, o);
        }
        float x1A = __expf(qA1 * inv_sqrt_d);
        float x2A = __expf(qA2 * inv_sqrt_d);
        float x3A = __expf(qA3 * inv_sqrt_d);
        float x4A = __expf(qA4 * inv_sqrt_d);
        float mB  = vB ? 1.f : 0.f;
        float x1B = __expf(qB1 * inv_sqrt_d) * mB;
        float x2B = __expf(qB2 * inv_sqrt_d);
        float x3B = __expf(qB3 * inv_sqrt_d) * mB;
        float x4B = __expf(qB4 * inv_sqrt_d);

        a1l.x += x1A*(ibA0.x+pkA0.x) + x1B*(ibB0.x+pkB0.x);
        a1l.y += x1A*(ibA0.y+pkA0.y) + x1B*(ibB0.y+pkB0.y);
        a1l.z += x1A*(ibA0.z+pkA0.z) + x1B*(ibB0.z+pkB0.z);
        a1l.w += x1A*(ibA0.w+pkA0.w) + x1B*(ibB0.w+pkB0.w);
        a1h.x += x1A*(ibA1.x+pkA1.x) + x1B*(ibB1.x+pkB1.x);
        a1h.y += x1A*(ibA1.y+pkA1.y) + x1B*(ibB1.y+pkB1.y);
        a1h.z += x1A*(ibA1.z+pkA1.z) + x1B*(ibB1.z+pkB1.z);
        a1h.w += x1A*(ibA1.w+pkA1.w) + x1B*(ibB1.w+pkB1.w);
        a3l.x += x3A*(iaA0.x+1.f) + x3B*(iaB0.x+1.f);
        a3l.y += x3A*(iaA0.y+1.f) + x3B*(iaB0.y+1.f);
        a3l.z += x3A*(iaA0.z+1.f) + x3B*(iaB0.z+1.f);
        a3l.w += x3A*(iaA0.w+1.f) + x3B*(iaB0.w+1.f);
        a3h.x += x3A*(iaA1.x+1.f) + x3B*(iaB1.x+1.f);
        a3h.y += x3A*(iaA1.y+1.f) + x3B*(iaB1.y+1.f);
        a3h.z += x3A*(iaA1.z+1.f) + x3B*(iaB1.z+1.f);
        a3h.w += x3A*(iaA1.w+1.f) + x3B*(iaB1.w+1.f);
        s1 += x1A + x1B; s3 += x3A + x3B;
        if (q == 0) {
            x24[rA.y] = make_float2(x2A, x4A);
            if (vB) x24[rB.y] = make_float2(x2B, x4B);
        }
        eA = eA2; eB = eB2; vA = vA2; vB = vB2; rA = rA2; rB = rB2;
    }
    float r1 = (s1 > 0.f) ? 1.f / s1 : 0.f;
    float r3 = (s3 > 0.f) ? 1.f / s3 : 0.f;
    float4* oL = (float4*)(hLu + (size_t)uid * 128);
    float4* oS = (float4*)(hSu + (size_t)uid * 128);
    oL[q]      = make_float4(a1l.x*r1, a1l.y*r1, a1l.z*r1, a1l.w*r1);
    oL[q + 16] = make_float4(a1h.x*r1, a1h.y*r1, a1h.z*r1, a1h.w*r1);
    oS[q]      = make_float4(a3l.x*r3, a3l.y*r3, a3l.z*r3, a3l.w*r3);
    oS[q + 16] = make_float4(a3h.x*r3, a3h.y*r3, a3h.z*r3, a3h.w*r3);
}

// ----------------------- gather_i: 16-lane group per item -------------------
__global__ __launch_bounds__(256) void gather_i_kernel(
    const unsigned short* __restrict__ fusedU,   // [U,256] bf16 interleaved
    const float* __restrict__ pVui,
    const int2* __restrict__ lst, const int* __restrict__ off_i,
    const float2* __restrict__ x24,
    float* __restrict__ hLi, float* __restrict__ hSi, int I)
{
    const int wv   = (int)(((size_t)blockIdx.x * blockDim.x + threadIdx.x) >> 6);
    const int lane = threadIdx.x & 63;
    const int g = lane >> 4;
    const int q = lane & 15;
    const int iid = wv * 4 + g;
    if (iid >= I) return;

    float4 a2l = make_float4(0.f,0.f,0.f,0.f), a2h = make_float4(0.f,0.f,0.f,0.f);
    float4 a4l = make_float4(0.f,0.f,0.f,0.f), a4h = make_float4(0.f,0.f,0.f,0.f);
    float s2 = 0.f, s4 = 0.f;
    const int e0 = off_i[iid], e1 = off_i[iid + 1];

    int eA = e0, eB = e0 + 1;
    bool vA = eA < e1, vB = eB < e1;
    int2 rA = vA ? lst[eA] : make_int2(0, 0);
    int2 rB = vB ? lst[eB] : rA;
    float2 xA = vA ? x24[rA.y] : make_float2(0.f, 0.f);
    float2 xB = vB ? x24[rB.y] : make_float2(0.f, 0.f);

    while (vA) {
        int eA2 = eA + 2, eB2 = eB + 2;
        bool vA2 = eA2 < e1, vB2 = eB2 < e1;
        int2 rA2 = vA2 ? lst[eA2] : make_int2(0, 0);
        int2 rB2 = vB2 ? lst[eB2] : rA2;
        float2 xA2v = vA2 ? x24[rA2.y] : make_float2(0.f, 0.f);
        float2 xB2v = vB2 ? x24[rB2.y] : make_float2(0.f, 0.f);

        const uint4* fUA = (const uint4*)(fusedU + (size_t)rA.x * 256);
        const float* pvA = pVui + (size_t)rA.y * 128;
        const uint4* fUB = (const uint4*)(fusedU + (size_t)rB.x * 256);
        const float* pvB = pVui + (size_t)rB.y * 128;

        uint4 uaAp = fUA[q], ubAp = fUA[16 + q];
        uint4 uaBp = fUB[q], ubBp = fUB[16 + q];
        float4 pvA0 = nt_load4(pvA + q * 4), pvA1 = nt_load4(pvA + 64 + q * 4);
        float4 pvB0 = nt_load4(pvB + q * 4), pvB1 = nt_load4(pvB + 64 + q * 4);

        float4 uaA0, uaA1, ubA0, ubA1, uaB0, uaB1, ubB0, ubB1;
        bfu(uaAp, uaA0, uaA1); bfu(ubAp, ubA0, ubA1);
        bfu(uaBp, uaB0, uaB1); bfu(ubBp, ubB0, ubB1);

        if (!vB) { xB.x = 0.f; xB.y = 0.f; }
        a2l.x += xA.x*(ubA0.x+pvA0.x) + xB.x*(ubB0.x+pvB0.x);
        a2l.y += xA.x*(ubA0.y+pvA0.y) + xB.x*(ubB0.y+pvB0.y);
        a2l.z += xA.x*(ubA0.z+pvA0.z) + xB.x*(ubB0.z+pvB0.z);
        a2l.w += xA.x*(ubA0.w+pvA0.w) + xB.x*(ubB0.w+pvB0.w);
        a2h.x += xA.x*(ubA1.x+pvA1.x) + xB.x*(ubB1.x+pvB1.x);
        a2h.y += xA.x*(ubA1.y+pvA1.y) + xB.x*(ubB1.y+pvB1.y);
        a2h.z += xA.x*(ubA1.z+pvA1.z) + xB.x*(ubB1.z+pvB1.z);
        a2h.w += xA.x*(ubA1.w+pvA1.w) + xB.x*(ubB1.w+pvB1.w);
        a4l.x += xA.y*(uaA0.x+1.f) + xB.y*(uaB0.x+1.f);
        a4l.y += xA.y*(uaA0.y+1.f) + xB.y*(uaB0.y+1.f);
        a4l.z += xA.y*(uaA0.z+1.f) + xB.y*(uaB0.z+1.f);
        a4l.w += xA.y*(uaA0.w+1.f) + xB.y*(uaB0.w+1.f);
        a4h.x += xA.y*(uaA1.x+1.f) + xB.y*(uaB1.x+1.f);
        a4h.y += xA.y*(uaA1.y+1.f) + xB.y*(uaB1.y+1.f);
        a4h.z += xA.y*(uaA1.z+1.f) + xB.y*(uaB1.z+1.f);
        a4h.w += xA.y*(uaA1.w+1.f) + xB.y*(uaB1.w+1.f);
        s2 += xA.x + xB.x; s4 += xA.y + xB.y;

        eA = eA2; eB = eB2; vA = vA2; vB = vB2;
        rA = rA2; rB = rB2; xA = xA2v; xB = xB2v;
    }
    float r2 = (s2 > 0.f) ? 1.f / s2 : 0.f;
    float r4 = (s4 > 0.f) ? 1.f / s4 : 0.f;
    float4* oL = (float4*)(hLi + (size_t)iid * 128);
    float4* oS = (float4*)(hSi + (size_t)iid * 128);
    oL[q]      = make_float4(a2l.x*r2, a2l.y*r2, a2l.z*r2, a2l.w*r2);
    oL[q + 16] = make_float4(a2h.x*r2, a2h.y*r2, a2h.z*r2, a2h.w*r2);
    oS[q]      = make_float4(a4l.x*r4, a4l.y*r4, a4l.z*r4, a4l.w*r4);
    oS[q + 16] = make_float4(a4h.x*r4, a4h.y*r4, a4h.z*r4, a4h.w*r4);
}

// ---------------------------------------------------------------------------
extern "C" void kernel_launch(void* const* d_in, const int* in_sizes, int n_in,
                              void* d_out, int out_size, void* d_ws, size_t ws_size,
                              hipStream_t stream)
{
    const float* u_emb = (const float*)d_in[0];
    const float* i_emb = (const float*)d_in[1];
    const float* pVui  = (const float*)d_in[2];
    const float* pKiu  = (const float*)d_in[3];
    const float* w1    = (const float*)d_in[4];
    const float* w2    = (const float*)d_in[5];
    const float* w1b   = (const float*)d_in[6];
    const float* w2b   = (const float*)d_in[7];
    const float* w3    = (const float*)d_in[8];
    const float* w4    = (const float*)d_in[9];
    const int* edge_index = (const int*)d_in[10];
    const int* last_u     = (const int*)d_in[11];
    const int* last_i     = (const int*)d_in[12];

    const int U = in_sizes[0] / 128;
    const int I = in_sizes[1] / 128;
    const int E = in_sizes[10] / 2;
    const int nbu = (U + WB - 1) / WB;
    const int nbi = (I + WB - 1) / WB;

    unsigned short* us = (unsigned short*)d_ws;
    unsigned short* fusedU    = us;  us += (size_t)U * 256;
    unsigned short* fusedI    = us;  us += (size_t)I * 256;
    unsigned short* last_item = us;  us += (size_t)U * 128;
    unsigned short* last_user = us;  us += (size_t)I * 128;
    float* ws = (float*)us;
    float2* x24 = (float2*)ws;  ws += (size_t)E * 2;
    int2* eu_list = (int2*)ws;  ws += (size_t)E * 2;
    int2* ei_list = (int2*)ws;  ws += (size_t)E * 2;
    int* ip = (int*)ws;
    int* deg_u   = ip;  ip += U;
    int* deg_i   = ip;  ip += I;
    int* off_u   = ip;  ip += U + 1;
    int* off_i   = ip;  ip += I + 1;
    int* cur_u   = ip;  ip += U;
    int* cur_i   = ip;  ip += I;
    int* bsum    = ip;  ip += nbu + nbi;
    int* bscan   = ip;  ip += nbu + nbi;

    float* hLu = (float*)d_out;
    float* hSu = hLu + (size_t)U * 128;
    float* hLi = hSu + (size_t)U * 128;
    float* hSi = hLi + (size_t)I * 128;

    hipMemsetAsync(deg_u, 0, (size_t)(U + I) * sizeof(int), stream);

    dim3 blk(256);
    const int eblk = (E + 255) / 256;
    hist_kernel<<<eblk, blk, 0, stream>>>(edge_index, E, deg_u, deg_i);
    scan_blocksums_kernel<<<nbu + nbi, blk, 0, stream>>>(deg_u, U, nbu, deg_i, I, bsum);
    scan_partials_kernel<<<2, 64, 0, stream>>>(bsum, bscan, nbu, nbi, off_u, U, off_i, I);
    scan_final_kernel<<<nbu + nbi, blk, 0, stream>>>(
        deg_u, U, nbu, deg_i, I, bscan, off_u, cur_u, off_i, cur_i);
    scatter_ids_kernel<<<eblk, blk, 0, stream>>>(
        edge_index, E, cur_u, cur_i, eu_list, ei_list);

    Gemm6Desc gd;
    gd.X[0] = u_emb; gd.W[0] = w2;  gd.O[0] = fusedU;       gd.g[0] = nullptr;    gd.ostride[0] = 256; gd.nrows[0] = U;
    gd.X[1] = u_emb; gd.W[1] = w2b; gd.O[1] = fusedU + 128; gd.g[1] = nullptr;    gd.ostride[1] = 256; gd.nrows[1] = U;
    gd.X[2] = i_emb; gd.W[2] = w1;  gd.O[2] = fusedI;       gd.g[2] = nullptr;    gd.ostride[2] = 256; gd.nrows[2] = I;
    gd.X[3] = i_emb; gd.W[3] = w1b; gd.O[3] = fusedI + 128; gd.g[3] = nullptr;    gd.ostride[3] = 256; gd.nrows[3] = I;
    gd.X[4] = i_emb; gd.W[4] = w3;  gd.O[4] = last_item;    gd.g[4] = last_u + U; gd.ostride[4] = 128; gd.nrows[4] = U;
    gd.X[5] = u_emb; gd.W[5] = w4;  gd.O[5] = last_user;    gd.g[5] = last_i + I; gd.ostride[5] = 128; gd.nrows[5] = I;
    int maxrows = (U > I) ? U : I;
    dim3 ggrid((maxrows + 63) / 64, 6);
    gemm6_kernel<<<ggrid, blk, 0, stream>>>(gd);

    const float inv_sqrt_d = 1.0f / sqrtf(128.0f);
    gather_u_kernel<<<(U + 15) / 16, blk, 0, stream>>>(
        fusedU, fusedI, last_item, last_user, pVui, pKiu, eu_list, off_u,
        x24, hLu, hSu, U, inv_sqrt_d);
    gather_i_kernel<<<(I + 15) / 16, blk, 0, stream>>>(
        fusedU, pVui, ei_list, off_i, x24, hLi, hSi, I);
}

// Round 13
// 709.297 us; speedup vs baseline: 1.3534x; 1.0026x over previous
//
#include <hip/hip_runtime.h>
#include <hip/hip_bf16.h>
#include <math.h>

// ---------------------------------------------------------------------------
// DGSR layer, MI355X. H = 128 fixed.
//   0. zero_kernel: custom zeroing of degree arrays (hipMemsetAsync's
//      fillBufferAligned took 234us/replay under graph capture!)
//   1. CSR build: histogram -> 3-kernel scan -> scatter of int2 (partner,eid)
//   2. gemm6: fused 6 projections, epilogue writes BF16 tables in an
//      INTERLEAVED layout: each 128-col block stored as 16 x 16B chunks,
//      chunk q = {elems 4q..4q+3, elems 64+4q..64+4q+3}. A single uint4
//      load per lane is contiguous AND matches the f32 p-row layout
//      (float4 at [4q] and [64+4q] -> two contiguous 256B segments).
//   3. gather_u: 16-lane group per user (4/wave), unroll x2 + record
//      prefetch. All 5 logit dots in-reg (4 chains, 4-stage shfl),
//      accumulates hLu/hSu, writes x24[eid]=(x2,x4).
//   4. gather_i: 16-lane group per item, pure streaming accumulate.
// exp without max-subtraction (logits ~N(0,1.4)). No f32 atomics anywhere.
// ---------------------------------------------------------------------------

#define WB 1024  // elements per scan block

typedef float fvec4 __attribute__((ext_vector_type(4)));

__device__ __forceinline__ float4 nt_load4(const float* p) {
    fvec4 v = __builtin_nontemporal_load((const fvec4*)p);
    return make_float4(v.x, v.y, v.z, v.w);
}
__device__ __forceinline__ float dot4(float4 a, float4 b) {
    return a.x * b.x + a.y * b.y + a.z * b.z + a.w * b.w;
}
// unpack 8 bf16 (uint4 = one interleaved chunk) -> lo4 (elems 4q..) hi4 (64+4q..)
__device__ __forceinline__ void bfu(uint4 v, float4& lo, float4& hi) {
    lo.x = __uint_as_float(v.x << 16);
    lo.y = __uint_as_float(v.x & 0xFFFF0000u);
    lo.z = __uint_as_float(v.y << 16);
    lo.w = __uint_as_float(v.y & 0xFFFF0000u);
    hi.x = __uint_as_float(v.z << 16);
    hi.y = __uint_as_float(v.z & 0xFFFF0000u);
    hi.z = __uint_as_float(v.w << 16);
    hi.w = __uint_as_float(v.w & 0xFFFF0000u);
}
__device__ __forceinline__ unsigned rne16(float f) {
    unsigned u = __float_as_uint(f);
    return (u + 0x7FFFu + ((u >> 16) & 1u)) >> 16;
}
__device__ __forceinline__ unsigned pack2(float a, float b) {
    return rne16(a) | (rne16(b) << 16);
}

// ----------------------- zeroing (replaces pathological hipMemsetAsync) -----
__global__ __launch_bounds__(256) void zero_kernel(int* __restrict__ p, int n)
{
    int i = blockIdx.x * 256 + threadIdx.x;
    if (i < n) p[i] = 0;
}

// ----------------------- fused 6x GEMM -> interleaved bf16 tables -----------
struct Gemm6Desc {
    const float* X[6];
    const float* W[6];
    unsigned short* O[6];
    const int*   g[6];
    int          ostride[6];
    int          nrows[6];
};

__global__ __launch_bounds__(256) void gemm6_kernel(Gemm6Desc d)
{
    __shared__ float Xl[64 * 32];
    __shared__ float Wl[128 * 32];
    const int j6 = blockIdx.y;
    const float* __restrict__ X = d.X[j6];
    const float* __restrict__ W = d.W[j6];
    unsigned short* __restrict__ O = d.O[j6];
    const int* __restrict__ gidx = d.g[j6];
    const int ostride = d.ostride[j6];
    const int nrows   = d.nrows[j6];

    const int t  = threadIdx.x;
    const int tx = t & 15;
    const int ty = t >> 4;
    const int brow = blockIdx.x * 64;
    if (brow >= nrows) return;

    float acc[4][8];
#pragma unroll
    for (int j = 0; j < 4; ++j)
#pragma unroll
        for (int i = 0; i < 8; ++i) acc[j][i] = 0.f;

    for (int k0 = 0; k0 < 128; k0 += 32) {
        __syncthreads();
#pragma unroll
        for (int u = 0; u < 2; ++u) {
            int idx4 = t + u * 256;
            int r  = idx4 >> 3;
            int k4 = idx4 & 7;
            int row = brow + r;
            float4 v = make_float4(0.f, 0.f, 0.f, 0.f);
            if (row < nrows) {
                int g = gidx ? gidx[row] : row;
                v = *(const float4*)(X + (size_t)g * 128 + k0 + k4 * 4);
            }
            int sw = k4 ^ ((r >> 3) & 7);
            *(float4*)(Xl + r * 32 + sw * 4) = v;
        }
#pragma unroll
        for (int u = 0; u < 4; ++u) {
            int idx4 = t + u * 256;
            int c  = idx4 >> 3;
            int k4 = idx4 & 7;
            float4 v = *(const float4*)(W + (size_t)c * 128 + k0 + k4 * 4);
            int sw = k4 ^ ((c >> 3) & 7);
            *(float4*)(Wl + c * 32 + sw * 4) = v;
        }
        __syncthreads();
#pragma unroll
        for (int k4 = 0; k4 < 8; ++k4) {
            float4 xv[4], wv[8];
#pragma unroll
            for (int j = 0; j < 4; ++j) {
                int r = ty * 4 + j;
                xv[j] = *(const float4*)(Xl + r * 32 + ((k4 ^ ((r >> 3) & 7)) * 4));
            }
#pragma unroll
            for (int i = 0; i < 8; ++i) {
                int c = tx * 8 + i;
                wv[i] = *(const float4*)(Wl + c * 32 + ((k4 ^ ((c >> 3) & 7)) * 4));
            }
#pragma unroll
            for (int j = 0; j < 4; ++j)
#pragma unroll
                for (int i = 0; i < 8; ++i) {
                    acc[j][i] += xv[j].x * wv[i].x;
                    acc[j][i] += xv[j].y * wv[i].y;
                    acc[j][i] += xv[j].z * wv[i].z;
                    acc[j][i] += xv[j].w * wv[i].w;
                }
        }
    }
    // interleaved epilogue: cols 8tx..8tx+3 and 8tx+4..8tx+7 go to the lo
    // (tx<8) or hi (tx>=8) 8B halves of chunks 2tx(') and 2tx(')+1.
    const int base = (tx < 8) ? (16 * tx) : (16 * (tx - 8) + 4);
#pragma unroll
    for (int j = 0; j < 4; ++j) {
        int row = brow + ty * 4 + j;
        if (row < nrows) {
            unsigned short* op = O + (size_t)row * ostride;
            uint2 lo, hi;
            lo.x = pack2(acc[j][0], acc[j][1]);
            lo.y = pack2(acc[j][2], acc[j][3]);
            hi.x = pack2(acc[j][4], acc[j][5]);
            hi.y = pack2(acc[j][6], acc[j][7]);
            *(uint2*)(op + base)     = lo;
            *(uint2*)(op + base + 8) = hi;
        }
    }
}

// ----------------------- CSR build ------------------------------------------
__global__ __launch_bounds__(256) void hist_kernel(
    const int* __restrict__ ei, int E,
    int* __restrict__ deg_u, int* __restrict__ deg_i)
{
    int e = blockIdx.x * 256 + threadIdx.x;
    if (e < E) {
        atomicAdd(&deg_u[ei[e]], 1);
        atomicAdd(&deg_i[ei[E + e]], 1);
    }
}

__global__ __launch_bounds__(256) void scan_blocksums_kernel(
    const int* __restrict__ deg_u, int nu, int nbu,
    const int* __restrict__ deg_i, int ni,
    int* __restrict__ bsum)
{
    int b = blockIdx.x;
    const int* deg; int n; int base;
    if (b < nbu) { deg = deg_u; n = nu; base = b * WB; }
    else         { deg = deg_i; n = ni; base = (b - nbu) * WB; }
    int t = threadIdx.x;
    int s = 0;
#pragma unroll
    for (int j = 0; j < 4; ++j) {
        int i = base + t * 4 + j;
        if (i < n) s += deg[i];
    }
#pragma unroll
    for (int o = 32; o > 0; o >>= 1) s += __shfl_xor(s, o);
    __shared__ int wt[4];
    if ((t & 63) == 0) wt[t >> 6] = s;
    __syncthreads();
    if (t == 0) bsum[b] = wt[0] + wt[1] + wt[2] + wt[3];
}

__global__ void scan_partials_kernel(
    const int* __restrict__ bsum, int* __restrict__ bscan,
    int nbu, int nbi,
    int* __restrict__ off_u, int nu, int* __restrict__ off_i, int ni)
{
    if (threadIdx.x != 0) return;
    if (blockIdx.x == 0) {
        int c = 0;
        for (int b = 0; b < nbu; ++b) { bscan[b] = c; c += bsum[b]; }
        off_u[nu] = c;
    } else {
        int c = 0;
        for (int b = 0; b < nbi; ++b) { bscan[nbu + b] = c; c += bsum[nbu + b]; }
        off_i[ni] = c;
    }
}

__global__ __launch_bounds__(256) void scan_final_kernel(
    const int* __restrict__ deg_u, int nu, int nbu,
    const int* __restrict__ deg_i, int ni,
    const int* __restrict__ bscan,
    int* __restrict__ off_u, int* __restrict__ cur_u,
    int* __restrict__ off_i, int* __restrict__ cur_i)
{
    int b = blockIdx.x;
    const int* deg; int n; int base; int* off; int* cur;
    if (b < nbu) { deg = deg_u; n = nu; base = b * WB; off = off_u; cur = cur_u; }
    else         { deg = deg_i; n = ni; base = (b - nbu) * WB; off = off_i; cur = cur_i; }
    int t = threadIdx.x;
    int lane = t & 63, w = t >> 6;
    int v[4];
    int s = 0;
#pragma unroll
    for (int j = 0; j < 4; ++j) {
        int i = base + t * 4 + j;
        v[j] = (i < n) ? deg[i] : 0;
        s += v[j];
    }
    int inc = s;
#pragma unroll
    for (int o = 1; o < 64; o <<= 1) {
        int x = __shfl_up(inc, o);
        if (lane >= o) inc += x;
    }
    int excl = inc - s;
    __shared__ int wt[4];
    if (lane == 63) wt[w] = inc;
    __syncthreads();
    int wbase = 0;
    for (int j = 0; j < w; ++j) wbase += wt[j];
    int e = bscan[b] + wbase + excl;
#pragma unroll
    for (int j = 0; j < 4; ++j) {
        int i = base + t * 4 + j;
        if (i < n) { off[i] = e; cur[i] = e; }
        e += v[j];
    }
}

__global__ __launch_bounds__(256) void scatter_ids_kernel(
    const int* __restrict__ ei, int E,
    int* __restrict__ cur_u, int* __restrict__ cur_i,
    int2* __restrict__ eu_list, int2* __restrict__ ei_list)
{
    int e = blockIdx.x * 256 + threadIdx.x;
    if (e < E) {
        int u = ei[e], v = ei[E + e];
        int pu = atomicAdd(&cur_u[u], 1);
        eu_list[pu] = make_int2(v, e);   // (item, eid)
        int pi = atomicAdd(&cur_i[v], 1);
        ei_list[pi] = make_int2(u, e);   // (user, eid)
    }
}

// ----------------------- gather_u: 16-lane group per user -------------------
__global__ __launch_bounds__(256) void gather_u_kernel(
    const unsigned short* __restrict__ fusedU,   // [U,256] bf16 interleaved
    const unsigned short* __restrict__ fusedI,   // [I,256] bf16 interleaved
    const unsigned short* __restrict__ last_item,
    const unsigned short* __restrict__ last_user,
    const float* __restrict__ pVui, const float* __restrict__ pKiu,
    const int2* __restrict__ lst, const int* __restrict__ off_u,
    float2* __restrict__ x24,
    float* __restrict__ hLu, float* __restrict__ hSu, int U, float inv_sqrt_d)
{
    const int wv   = (int)(((size_t)blockIdx.x * blockDim.x + threadIdx.x) >> 6);
    const int lane = threadIdx.x & 63;
    const int g = lane >> 4;   // user group within wave
    const int q = lane & 15;   // chunk slot: elems {4q..4q+3, 64+4q..64+4q+3}
    const int uid = wv * 4 + g;
    if (uid >= U) return;

    float4 um0, um1, li0, li1, lu0, lu1;
    bfu(((const uint4*)(fusedU    + (size_t)uid * 256))[q], um0, um1);
    bfu(((const uint4*)(last_item + (size_t)uid * 128))[q], li0, li1);
    bfu(((const uint4*)(last_user + (size_t)uid * 128))[q], lu0, lu1);

    float4 a1l = make_float4(0.f,0.f,0.f,0.f), a1h = make_float4(0.f,0.f,0.f,0.f);
    float4 a3l = make_float4(0.f,0.f,0.f,0.f), a3h = make_float4(0.f,0.f,0.f,0.f);
    float s1 = 0.f, s3 = 0.f;
    const int e0 = off_u[uid], e1 = off_u[uid + 1];

    int eA = e0, eB = e0 + 1;
    bool vA = eA < e1, vB = eB < e1;
    int2 rA = vA ? lst[eA] : make_int2(0, 0);
    int2 rB = vB ? lst[eB] : rA;

    while (vA) {
        int eA2 = eA + 2, eB2 = eB + 2;
        bool vA2 = eA2 < e1, vB2 = eB2 < e1;
        int2 rA2 = vA2 ? lst[eA2] : make_int2(0, 0);
        int2 rB2 = vB2 ? lst[eB2] : rA2;

        const uint4* fIA = (const uint4*)(fusedI + (size_t)rA.x * 256);
        const float* pvA = pVui + (size_t)rA.y * 128;
        const float* pkA = pKiu + (size_t)rA.y * 128;
        const uint4* fIB = (const uint4*)(fusedI + (size_t)rB.x * 256);
        const float* pvB = pVui + (size_t)rB.y * 128;
        const float* pkB = pKiu + (size_t)rB.y * 128;

        uint4 iaAp = fIA[q], ibAp = fIA[16 + q];
        uint4 iaBp = fIB[q], ibBp = fIB[16 + q];
        float4 pvA0 = nt_load4(pvA + q * 4), pvA1 = nt_load4(pvA + 64 + q * 4);
        float4 pkA0 = nt_load4(pkA + q * 4), pkA1 = nt_load4(pkA + 64 + q * 4);
        float4 pvB0 = nt_load4(pvB + q * 4), pvB1 = nt_load4(pvB + 64 + q * 4);
        float4 pkB0 = nt_load4(pkB + q * 4), pkB1 = nt_load4(pkB + 64 + q * 4);

        float4 iaA0, iaA1, ibA0, ibA1, iaB0, iaB1, ibB0, ibB1;
        bfu(iaAp, iaA0, iaA1); bfu(ibAp, ibA0, ibA1);
        bfu(iaBp, iaB0, iaB1); bfu(ibBp, ibB0, ibB1);

        float dA0 = dot4(um0, iaA0) + dot4(um1, iaA1);
        float qA1 = dA0 + dot4(um0, pvA0) + dot4(um1, pvA1);
        float qA2 = dA0 + dot4(iaA0, pkA0) + dot4(iaA1, pkA1);
        float qA3 = dot4(li0, iaA0) + dot4(li1, iaA1);
        float qA4 = dot4(lu0, iaA0) + dot4(lu1, iaA1);
        float dB0 = dot4(um0, iaB0) + dot4(um1, iaB1);
        float qB1 = dB0 + dot4(um0, pvB0) + dot4(um1, pvB1);
        float qB2 = dB0 + dot4(iaB0, pkB0) + dot4(iaB1, pkB1);
        float qB3 = dot4(li0, iaB0) + dot4(li1, iaB1);
        float qB4 = dot4(lu0, iaB0) + dot4(lu1, iaB1);
#pragma unroll
        for (int o = 8; o > 0; o >>= 1) {
            qA1 += __shfl_xor(qA1, o); qA2 += __shfl_xor(qA2, o);
            qA3 += __shfl_xor(qA3, o); qA4 += __shfl_xor(qA4, o);
            qB1 += __shfl_xor(qB1, o); qB2 += __shfl_xor(qB2, o);
            qB3 += __shfl_xor(qB3, o); qB4 += __shfl_xor(qB4, o);
        }
        float x1A = __expf(qA1 * inv_sqrt_d);
        float x2A = __expf(qA2 * inv_sqrt_d);
        float x3A = __expf(qA3 * inv_sqrt_d);
        float x4A = __expf(qA4 * inv_sqrt_d);
        float mB  = vB ? 1.f : 0.f;
        float x1B = __expf(qB1 * inv_sqrt_d) * mB;
        float x2B = __expf(qB2 * inv_sqrt_d);
        float x3B = __expf(qB3 * inv_sqrt_d) * mB;
        float x4B = __expf(qB4 * inv_sqrt_d);

        a1l.x += x1A*(ibA0.x+pkA0.x) + x1B*(ibB0.x+pkB0.x);
        a1l.y += x1A*(ibA0.y+pkA0.y) + x1B*(ibB0.y+pkB0.y);
        a1l.z += x1A*(ibA0.z+pkA0.z) + x1B*(ibB0.z+pkB0.z);
        a1l.w += x1A*(ibA0.w+pkA0.w) + x1B*(ibB0.w+pkB0.w);
        a1h.x += x1A*(ibA1.x+pkA1.x) + x1B*(ibB1.x+pkB1.x);
        a1h.y += x1A*(ibA1.y+pkA1.y) + x1B*(ibB1.y+pkB1.y);
        a1h.z += x1A*(ibA1.z+pkA1.z) + x1B*(ibB1.z+pkB1.z);
        a1h.w += x1A*(ibA1.w+pkA1.w) + x1B*(ibB1.w+pkB1.w);
        a3l.x += x3A*(iaA0.x+1.f) + x3B*(iaB0.x+1.f);
        a3l.y += x3A*(iaA0.y+1.f) + x3B*(iaB0.y+1.f);
        a3l.z += x3A*(iaA0.z+1.f) + x3B*(iaB0.z+1.f);
        a3l.w += x3A*(iaA0.w+1.f) + x3B*(iaB0.w+1.f);
        a3h.x += x3A*(iaA1.x+1.f) + x3B*(iaB1.x+1.f);
        a3h.y += x3A*(iaA1.y+1.f) + x3B*(iaB1.y+1.f);
        a3h.z += x3A*(iaA1.z+1.f) + x3B*(iaB1.z+1.f);
        a3h.w += x3A*(iaA1.w+1.f) + x3B*(iaB1.w+1.f);
        s1 += x1A + x1B; s3 += x3A + x3B;
        if (q == 0) {
            x24[rA.y] = make_float2(x2A, x4A);
            if (vB) x24[rB.y] = make_float2(x2B, x4B);
        }
        eA = eA2; eB = eB2; vA = vA2; vB = vB2; rA = rA2; rB = rB2;
    }
    float r1 = (s1 > 0.f) ? 1.f / s1 : 0.f;
    float r3 = (s3 > 0.f) ? 1.f / s3 : 0.f;
    float4* oL = (float4*)(hLu + (size_t)uid * 128);
    float4* oS = (float4*)(hSu + (size_t)uid * 128);
    oL[q]      = make_float4(a1l.x*r1, a1l.y*r1, a1l.z*r1, a1l.w*r1);
    oL[q + 16] = make_float4(a1h.x*r1, a1h.y*r1, a1h.z*r1, a1h.w*r1);
    oS[q]      = make_float4(a3l.x*r3, a3l.y*r3, a3l.z*r3, a3l.w*r3);
    oS[q + 16] = make_float4(a3h.x*r3, a3h.y*r3, a3h.z*r3, a3h.w*r3);
}

// ----------------------- gather_i: 16-lane group per item -------------------
__global__ __launch_bounds__(256) void gather_i_kernel(
    const unsigned short* __restrict__ fusedU,   // [U,256] bf16 interleaved
    const float* __restrict__ pVui,
    const int2* __restrict__ lst, const int* __restrict__ off_i,
    const float2* __restrict__ x24,
    float* __restrict__ hLi, float* __restrict__ hSi, int I)
{
    const int wv   = (int)(((size_t)blockIdx.x * blockDim.x + threadIdx.x) >> 6);
    const int lane = threadIdx.x & 63;
    const int g = lane >> 4;
    const int q = lane & 15;
    const int iid = wv * 4 + g;
    if (iid >= I) return;

    float4 a2l = make_float4(0.f,0.f,0.f,0.f), a2h = make_float4(0.f,0.f,0.f,0.f);
    float4 a4l = make_float4(0.f,0.f,0.f,0.f), a4h = make_float4(0.f,0.f,0.f,0.f);
    float s2 = 0.f, s4 = 0.f;
    const int e0 = off_i[iid], e1 = off_i[iid + 1];

    int eA = e0, eB = e0 + 1;
    bool vA = eA < e1, vB = eB < e1;
    int2 rA = vA ? lst[eA] : make_int2(0, 0);
    int2 rB = vB ? lst[eB] : rA;
    float2 xA = vA ? x24[rA.y] : make_float2(0.f, 0.f);
    float2 xB = vB ? x24[rB.y] : make_float2(0.f, 0.f);

    while (vA) {
        int eA2 = eA + 2, eB2 = eB + 2;
        bool vA2 = eA2 < e1, vB2 = eB2 < e1;
        int2 rA2 = vA2 ? lst[eA2] : make_int2(0, 0);
        int2 rB2 = vB2 ? lst[eB2] : rA2;
        float2 xA2v = vA2 ? x24[rA2.y] : make_float2(0.f, 0.f);
        float2 xB2v = vB2 ? x24[rB2.y] : make_float2(0.f, 0.f);

        const uint4* fUA = (const uint4*)(fusedU + (size_t)rA.x * 256);
        const float* pvA = pVui + (size_t)rA.y * 128;
        const uint4* fUB = (const uint4*)(fusedU + (size_t)rB.x * 256);
        const float* pvB = pVui + (size_t)rB.y * 128;

        uint4 uaAp = fUA[q], ubAp = fUA[16 + q];
        uint4 uaBp = fUB[q], ubBp = fUB[16 + q];
        float4 pvA0 = nt_load4(pvA + q * 4), pvA1 = nt_load4(pvA + 64 + q * 4);
        float4 pvB0 = nt_load4(pvB + q * 4), pvB1 = nt_load4(pvB + 64 + q * 4);

        float4 uaA0, uaA1, ubA0, ubA1, uaB0, uaB1, ubB0, ubB1;
        bfu(uaAp, uaA0, uaA1); bfu(ubAp, ubA0, ubA1);
        bfu(uaBp, uaB0, uaB1); bfu(ubBp, ubB0, ubB1);

        if (!vB) { xB.x = 0.f; xB.y = 0.f; }
        a2l.x += xA.x*(ubA0.x+pvA0.x) + xB.x*(ubB0.x+pvB0.x);
        a2l.y += xA.x*(ubA0.y+pvA0.y) + xB.x*(ubB0.y+pvB0.y);
        a2l.z += xA.x*(ubA0.z+pvA0.z) + xB.x*(ubB0.z+pvB0.z);
        a2l.w += xA.x*(ubA0.w+pvA0.w) + xB.x*(ubB0.w+pvB0.w);
        a2h.x += xA.x*(ubA1.x+pvA1.x) + xB.x*(ubB1.x+pvB1.x);
        a2h.y += xA.x*(ubA1.y+pvA1.y) + xB.x*(ubB1.y+pvB1.y);
        a2h.z += xA.x*(ubA1.z+pvA1.z) + xB.x*(ubB1.z+pvB1.z);
        a2h.w += xA.x*(ubA1.w+pvA1.w) + xB.x*(ubB1.w+pvB1.w);
        a4l.x += xA.y*(uaA0.x+1.f) + xB.y*(uaB0.x+1.f);
        a4l.y += xA.y*(uaA0.y+1.f) + xB.y*(uaB0.y+1.f);
        a4l.z += xA.y*(uaA0.z+1.f) + xB.y*(uaB0.z+1.f);
        a4l.w += xA.y*(uaA0.w+1.f) + xB.y*(uaB0.w+1.f);
        a4h.x += xA.y*(uaA1.x+1.f) + xB.y*(uaB1.x+1.f);
        a4h.y += xA.y*(uaA1.y+1.f) + xB.y*(uaB1.y+1.f);
        a4h.z += xA.y*(uaA1.z+1.f) + xB.y*(uaB1.z+1.f);
        a4h.w += xA.y*(uaA1.w+1.f) + xB.y*(uaB1.w+1.f);
        s2 += xA.x + xB.x; s4 += xA.y + xB.y;

        eA = eA2; eB = eB2; vA = vA2; vB = vB2;
        rA = rA2; rB = rB2; xA = xA2v; xB = xB2v;
    }
    float r2 = (s2 > 0.f) ? 1.f / s2 : 0.f;
    float r4 = (s4 > 0.f) ? 1.f / s4 : 0.f;
    float4* oL = (float4*)(hLi + (size_t)iid * 128);
    float4* oS = (float4*)(hSi + (size_t)iid * 128);
    oL[q]      = make_float4(a2l.x*r2, a2l.y*r2, a2l.z*r2, a2l.w*r2);
    oL[q + 16] = make_float4(a2h.x*r2, a2h.y*r2, a2h.z*r2, a2h.w*r2);
    oS[q]      = make_float4(a4l.x*r4, a4l.y*r4, a4l.z*r4, a4l.w*r4);
    oS[q + 16] = make_float4(a4h.x*r4, a4h.y*r4, a4h.z*r4, a4h.w*r4);
}

// ---------------------------------------------------------------------------
extern "C" void kernel_launch(void* const* d_in, const int* in_sizes, int n_in,
                              void* d_out, int out_size, void* d_ws, size_t ws_size,
                              hipStream_t stream)
{
    const float* u_emb = (const float*)d_in[0];
    const float* i_emb = (const float*)d_in[1];
    const float* pVui  = (const float*)d_in[2];
    const float* pKiu  = (const float*)d_in[3];
    const float* w1    = (const float*)d_in[4];
    const float* w2    = (const float*)d_in[5];
    const float* w1b   = (const float*)d_in[6];
    const float* w2b   = (const float*)d_in[7];
    const float* w3    = (const float*)d_in[8];
    const float* w4    = (const float*)d_in[9];
    const int* edge_index = (const int*)d_in[10];
    const int* last_u     = (const int*)d_in[11];
    const int* last_i     = (const int*)d_in[12];

    const int U = in_sizes[0] / 128;
    const int I = in_sizes[1] / 128;
    const int E = in_sizes[10] / 2;
    const int nbu = (U + WB - 1) / WB;
    const int nbi = (I + WB - 1) / WB;

    unsigned short* us = (unsigned short*)d_ws;
    unsigned short* fusedU    = us;  us += (size_t)U * 256;
    unsigned short* fusedI    = us;  us += (size_t)I * 256;
    unsigned short* last_item = us;  us += (size_t)U * 128;
    unsigned short* last_user = us;  us += (size_t)I * 128;
    float* ws = (float*)us;
    float2* x24 = (float2*)ws;  ws += (size_t)E * 2;
    int2* eu_list = (int2*)ws;  ws += (size_t)E * 2;
    int2* ei_list = (int2*)ws;  ws += (size_t)E * 2;
    int* ip = (int*)ws;
    int* deg_u   = ip;  ip += U;
    int* deg_i   = ip;  ip += I;
    int* off_u   = ip;  ip += U + 1;
    int* off_i   = ip;  ip += I + 1;
    int* cur_u   = ip;  ip += U;
    int* cur_i   = ip;  ip += I;
    int* bsum    = ip;  ip += nbu + nbi;
    int* bscan   = ip;  ip += nbu + nbi;

    float* hLu = (float*)d_out;
    float* hSu = hLu + (size_t)U * 128;
    float* hLi = hSu + (size_t)U * 128;
    float* hSi = hLi + (size_t)I * 128;

    dim3 blk(256);
    const int eblk = (E + 255) / 256;
    zero_kernel<<<(U + I + 255) / 256, blk, 0, stream>>>(deg_u, U + I);
    hist_kernel<<<eblk, blk, 0, stream>>>(edge_index, E, deg_u, deg_i);
    scan_blocksums_kernel<<<nbu + nbi, blk, 0, stream>>>(deg_u, U, nbu, deg_i, I, bsum);
    scan_partials_kernel<<<2, 64, 0, stream>>>(bsum, bscan, nbu, nbi, off_u, U, off_i, I);
    scan_final_kernel<<<nbu + nbi, blk, 0, stream>>>(
        deg_u, U, nbu, deg_i, I, bscan, off_u, cur_u, off_i, cur_i);
    scatter_ids_kernel<<<eblk, blk, 0, stream>>>(
        edge_index, E, cur_u, cur_i, eu_list, ei_list);

    Gemm6Desc gd;
    gd.X[0] = u_emb; gd.W[0] = w2;  gd.O[0] = fusedU;       gd.g[0] = nullptr;    gd.ostride[0] = 256; gd.nrows[0] = U;
    gd.X[1] = u_emb; gd.W[1] = w2b; gd.O[1] = fusedU + 128; gd.g[1] = nullptr;    gd.ostride[1] = 256; gd.nrows[1] = U;
    gd.X[2] = i_emb; gd.W[2] = w1;  gd.O[2] = fusedI;       gd.g[2] = nullptr;    gd.ostride[2] = 256; gd.nrows[2] = I;
    gd.X[3] = i_emb; gd.W[3] = w1b; gd.O[3] = fusedI + 128; gd.g[3] = nullptr;    gd.ostride[3] = 256; gd.nrows[3] = I;
    gd.X[4] = i_emb; gd.W[4] = w3;  gd.O[4] = last_item;    gd.g[4] = last_u + U; gd.ostride[4] = 128; gd.nrows[4] = U;
    gd.X[5] = u_emb; gd.W[5] = w4;  gd.O[5] = last_user;    gd.g[5] = last_i + I; gd.ostride[5] = 128; gd.nrows[5] = I;
    int maxrows = (U > I) ? U : I;
    dim3 ggrid((maxrows + 63) / 64, 6);
    gemm6_kernel<<<ggrid, blk, 0, stream>>>(gd);

    const float inv_sqrt_d = 1.0f / sqrtf(128.0f);
    gather_u_kernel<<<(U + 15) / 16, blk, 0, stream>>>(
        fusedU, fusedI, last_item, last_user, pVui, pKiu, eu_list, off_u,
        x24, hLu, hSu, U, inv_sqrt_d);
    gather_i_kernel<<<(I + 15) / 16, blk, 0, stream>>>(
        fusedU, pVui, ei_list, off_i, x24, hLi, hSi, I);
}